// Round 2
// baseline (666.237 us; speedup 1.0000x reference)
//
#include <hip/hip_runtime.h>

// ---------------------------------------------------------------------------
// GCN: 2x GCNConv (transform -> normalize-scaled scatter-add) + linear head
// Pipeline per launch:
//  1) deg histogram (atomics)  2) dinv = rsqrt(deg+1)
//  3) CSR build: per-block scan -> top scan -> finalize -> scatter
//  4) GEMM1 (x@W1, rows scaled by dinv)    -> M1'  [N,128]
//  5) SpMM1: h1 = relu(dinv[v]*(sum M1'[neigh] + M1'[v]) + b1)
//  6) GEMM2 (h1@W2, rows scaled by dinv)   -> M2'  [N,64]
//  7) SpMM2: h2 = relu(...)
//  8) head: logits = h2@Wl + bl, log_softmax
// NOTE: edge_index is int32 on device (JAX x64 disabled) -> const int*.
// ---------------------------------------------------------------------------

__global__ void deg_kernel(const int* __restrict__ dst, int* __restrict__ cnt,
                           int E, int n) {
    int stride = gridDim.x * blockDim.x;
    for (int e = blockIdx.x * blockDim.x + threadIdx.x; e < E; e += stride) {
        int d = dst[e];
        if (d >= 0 && d < n) atomicAdd(&cnt[d], 1);
    }
}

__global__ void dinv_kernel(const int* __restrict__ cnt, float* __restrict__ dinv, int n) {
    int v = blockIdx.x * blockDim.x + threadIdx.x;
    if (v < n) dinv[v] = rsqrtf((float)(cnt[v] + 1));   // +1 self loop; always > 0
}

// Per-block exclusive scan of cnt -> rowptr (local), block totals -> bsums
__global__ void scan_block(const int* __restrict__ cnt, int* __restrict__ rowptr,
                           int* __restrict__ bsums, int n) {
    __shared__ int s[256];
    int i = blockIdx.x * 256 + threadIdx.x;
    int v = (i < n) ? cnt[i] : 0;
    s[threadIdx.x] = v;
    __syncthreads();
    for (int off = 1; off < 256; off <<= 1) {
        int t = (threadIdx.x >= off) ? s[threadIdx.x - off] : 0;
        __syncthreads();
        s[threadIdx.x] += t;
        __syncthreads();
    }
    if (i < n) rowptr[i] = s[threadIdx.x] - v;          // exclusive within block
    if (threadIdx.x == 255) bsums[blockIdx.x] = s[255];
}

// Single-block scan of block sums (nb <= 512)
__global__ void scan_tops(const int* __restrict__ bsums, int* __restrict__ boffs, int nb) {
    __shared__ int s[512];
    int v = (threadIdx.x < nb) ? bsums[threadIdx.x] : 0;
    s[threadIdx.x] = v;
    __syncthreads();
    for (int off = 1; off < 512; off <<= 1) {
        int t = (threadIdx.x >= off) ? s[threadIdx.x - off] : 0;
        __syncthreads();
        s[threadIdx.x] += t;
        __syncthreads();
    }
    if (threadIdx.x < nb) boffs[threadIdx.x] = s[threadIdx.x] - v;
}

__global__ void finalize_rowptr(int* __restrict__ rowptr, const int* __restrict__ boffs,
                                int n, int E) {
    int i = blockIdx.x * 256 + threadIdx.x;
    if (i < n) rowptr[i] += boffs[blockIdx.x];
    if (i == 0) rowptr[n] = E;
}

__global__ void scatter_kernel(const int* __restrict__ src, const int* __restrict__ dst,
                               const int* __restrict__ rowptr, int* __restrict__ cur,
                               int* __restrict__ csr, int E, int n) {
    int stride = gridDim.x * blockDim.x;
    for (int e = blockIdx.x * blockDim.x + threadIdx.x; e < E; e += stride) {
        int d = dst[e];
        int s = src[e];
        if (d >= 0 && d < n && s >= 0 && s < n) {
            int p = atomicAdd(&cur[d], 1);
            csr[rowptr[d] + p] = s;
        }
    }
}

// Tiled fp32 GEMM: out[m][n] = dinv[m] * sum_k A[m][k]*B[k][n]
// BM=128, BN=64*NCH, BK=8, 256 threads (16x16), 8x(4*NCH) microtile per thread.
template<int BK, int NCH, int LDA, int LDB, int KDIM>
__global__ __launch_bounds__(256) void gemm_scale(
    const float* __restrict__ A, const float* __restrict__ B,
    const float* __restrict__ dinv, float* __restrict__ out, int M) {
    constexpr int BM = 128;
    constexpr int BN = 64 * NCH;
    __shared__ float As[BK * BM];   // transposed: As[k][m]
    __shared__ float Bs[BK * BN];   // Bs[k][n]
    const int tid = threadIdx.x;
    const int tx = tid & 15, ty = tid >> 4;
    const int m0 = blockIdx.x * BM;

    float acc[2][NCH][4][4] = {};

    for (int k0 = 0; k0 < KDIM; k0 += BK) {
        // stage A tile (BK*BM = 1024 floats = 256 float4)
        {
            int row = tid >> 1, kc = tid & 1;
            int gr = m0 + row; if (gr >= M) gr = M - 1;
            const float4 av = *(const float4*)&A[(size_t)gr * LDA + k0 + kc * 4];
            As[(kc * 4 + 0) * BM + row] = av.x;
            As[(kc * 4 + 1) * BM + row] = av.y;
            As[(kc * 4 + 2) * BM + row] = av.z;
            As[(kc * 4 + 3) * BM + row] = av.w;
        }
        // stage B tile
        {
            constexpr int NB4 = BK * BN / 4;
            if (NB4 >= 256 || tid < NB4) {
                int kr = tid / (BN / 4), nc = tid % (BN / 4);
                const float4 bv = *(const float4*)&B[(size_t)(k0 + kr) * LDB + nc * 4];
                *(float4*)&Bs[kr * BN + nc * 4] = bv;
            }
        }
        __syncthreads();
        #pragma unroll
        for (int k = 0; k < BK; k++) {
            float4 a0 = *(const float4*)&As[k * BM + ty * 4];
            float4 a1 = *(const float4*)&As[k * BM + 64 + ty * 4];
            float a[2][4] = {{a0.x, a0.y, a0.z, a0.w}, {a1.x, a1.y, a1.z, a1.w}};
            float b[NCH][4];
            #pragma unroll
            for (int in = 0; in < NCH; in++) {
                float4 bv = *(const float4*)&Bs[k * BN + in * 64 + tx * 4];
                b[in][0] = bv.x; b[in][1] = bv.y; b[in][2] = bv.z; b[in][3] = bv.w;
            }
            #pragma unroll
            for (int im = 0; im < 2; im++)
                #pragma unroll
                for (int in = 0; in < NCH; in++)
                    #pragma unroll
                    for (int i = 0; i < 4; i++)
                        #pragma unroll
                        for (int j = 0; j < 4; j++)
                            acc[im][in][i][j] += a[im][i] * b[in][j];
        }
        __syncthreads();
    }
    #pragma unroll
    for (int im = 0; im < 2; im++) {
        #pragma unroll
        for (int i = 0; i < 4; i++) {
            int m = m0 + im * 64 + ty * 4 + i;
            if (m < M) {
                float sc = dinv[m];
                #pragma unroll
                for (int in = 0; in < NCH; in++) {
                    float4 o;
                    o.x = acc[im][in][i][0] * sc;
                    o.y = acc[im][in][i][1] * sc;
                    o.z = acc[im][in][i][2] * sc;
                    o.w = acc[im][in][i][3] * sc;
                    *(float4*)&out[(size_t)m * BN + in * 64 + tx * 4] = o;
                }
            }
        }
    }
}

// Wave-per-node SpMM: out[v] = relu(dinv[v]*(sum_{s in csr[v]} M[s] + M[v]) + bias)
template<int F>
__global__ __launch_bounds__(256) void spmm_relu(
    const float* __restrict__ Mm, const int* __restrict__ rowptr,
    const int* __restrict__ csr, const float* __restrict__ dinv,
    const float* __restrict__ bias, float* __restrict__ out, int n) {
    int v = (blockIdx.x * 256 + threadIdx.x) >> 6;
    int lane = threadIdx.x & 63;
    if (v >= n) return;
    int jb = rowptr[v], je = rowptr[v + 1];
    if (F == 128) {
        int f = lane * 2;
        float2 acc0 = *(const float2*)&Mm[(size_t)v * 128 + f];   // self loop
        float2 acc1 = make_float2(0.f, 0.f);
        int j = jb;
        for (; j + 1 < je; j += 2) {
            int s0 = csr[j], s1 = csr[j + 1];
            float2 m0 = *(const float2*)&Mm[(size_t)s0 * 128 + f];
            float2 m1 = *(const float2*)&Mm[(size_t)s1 * 128 + f];
            acc0.x += m0.x; acc0.y += m0.y;
            acc1.x += m1.x; acc1.y += m1.y;
        }
        if (j < je) {
            int s0 = csr[j];
            float2 m0 = *(const float2*)&Mm[(size_t)s0 * 128 + f];
            acc0.x += m0.x; acc0.y += m0.y;
        }
        float d = dinv[v];
        float rx = fmaxf(d * (acc0.x + acc1.x) + bias[f], 0.f);
        float ry = fmaxf(d * (acc0.y + acc1.y) + bias[f + 1], 0.f);
        *(float2*)&out[(size_t)v * 128 + f] = make_float2(rx, ry);
    } else {
        float acc0 = Mm[(size_t)v * 64 + lane];                   // self loop
        float acc1 = 0.f;
        int j = jb;
        for (; j + 1 < je; j += 2) {
            int s0 = csr[j], s1 = csr[j + 1];
            acc0 += Mm[(size_t)s0 * 64 + lane];
            acc1 += Mm[(size_t)s1 * 64 + lane];
        }
        if (j < je) acc0 += Mm[(size_t)csr[j] * 64 + lane];
        float r = fmaxf(dinv[v] * (acc0 + acc1) + bias[lane], 0.f);
        out[(size_t)v * 64 + lane] = r;
    }
}

// logits = h2 @ Wl + bl ; out = log_softmax(logits)
__global__ __launch_bounds__(256) void head_kernel(
    const float* __restrict__ h2, const float* __restrict__ Wl,
    const float* __restrict__ bl, float* __restrict__ out, int n) {
    __shared__ float Ws[64 * 10];
    __shared__ float bs[10];
    for (int i = threadIdx.x; i < 640; i += 256) Ws[i] = Wl[i];
    if (threadIdx.x < 10) bs[threadIdx.x] = bl[threadIdx.x];
    __syncthreads();
    int v = blockIdx.x * 256 + threadIdx.x;
    if (v >= n) return;
    float acc[10];
    #pragma unroll
    for (int c = 0; c < 10; c++) acc[c] = bs[c];
    const float* hrow = &h2[(size_t)v * 64];
    #pragma unroll
    for (int k0 = 0; k0 < 64; k0 += 4) {
        float4 h = *(const float4*)&hrow[k0];
        float hv[4] = {h.x, h.y, h.z, h.w};
        #pragma unroll
        for (int kk = 0; kk < 4; kk++)
            #pragma unroll
            for (int c = 0; c < 10; c++)
                acc[c] += hv[kk] * Ws[(k0 + kk) * 10 + c];
    }
    float m = acc[0];
    #pragma unroll
    for (int c = 1; c < 10; c++) m = fmaxf(m, acc[c]);
    float s = 0.f;
    #pragma unroll
    for (int c = 0; c < 10; c++) s += expf(acc[c] - m);
    float lse = logf(s);
    #pragma unroll
    for (int c = 0; c < 10; c++) out[(size_t)v * 10 + c] = acc[c] - m - lse;
}

extern "C" void kernel_launch(void* const* d_in, const int* in_sizes, int n_in,
                              void* d_out, int out_size, void* d_ws, size_t ws_size,
                              hipStream_t stream) {
    const float* x   = (const float*)d_in[0];
    const int*   ei  = (const int*)d_in[1];      // int32! (JAX x64 disabled)
    const float* W1  = (const float*)d_in[2];
    const float* b1  = (const float*)d_in[3];
    const float* W2  = (const float*)d_in[4];
    const float* b2  = (const float*)d_in[5];
    const float* Wl  = (const float*)d_in[6];
    const float* bl  = (const float*)d_in[7];
    float*       out = (float*)d_out;

    const int N = in_sizes[0] / 256;   // 100000
    const int E = in_sizes[1] / 2;     // 1600000
    const int* srcI = ei;
    const int* dstI = ei + E;

    char* ws = (char*)d_ws;
    size_t off = 0;
    auto alloc = [&](size_t bytes) -> void* {
        void* p = ws + off;
        off = (off + bytes + 255) & ~(size_t)255;
        return p;
    };
    int*   cnt    = (int*)alloc((size_t)N * 4);
    int*   cur    = (int*)alloc((size_t)N * 4);
    int*   rowptr = (int*)alloc((size_t)(N + 1) * 4);
    float* dinv   = (float*)alloc((size_t)N * 4);
    int*   csr    = (int*)alloc((size_t)E * 4);
    int*   bsums  = (int*)alloc(512 * 4);
    int*   boffs  = (int*)alloc(512 * 4);
    float* bufA   = (float*)alloc((size_t)N * 128 * 4);   // M1' then M2'
    float* bufB   = (float*)alloc((size_t)N * 128 * 4);   // h1 then h2

    hipMemsetAsync(cnt, 0, (size_t)N * 4, stream);
    hipMemsetAsync(cur, 0, (size_t)N * 4, stream);

    const int nb = (N + 255) / 256;  // 391 <= 512
    deg_kernel<<<1024, 256, 0, stream>>>(dstI, cnt, E, N);
    dinv_kernel<<<(N + 255) / 256, 256, 0, stream>>>(cnt, dinv, N);
    scan_block<<<nb, 256, 0, stream>>>(cnt, rowptr, bsums, N);
    scan_tops<<<1, 512, 0, stream>>>(bsums, boffs, nb);
    finalize_rowptr<<<nb, 256, 0, stream>>>(rowptr, boffs, N, E);
    scatter_kernel<<<1024, 256, 0, stream>>>(srcI, dstI, rowptr, cur, csr, E, N);

    // layer 1: M1' = dinv .* (x @ W1); h1 = relu(dinv .* (A_sum M1') + b1)
    gemm_scale<8, 2, 256, 128, 256><<<(N + 127) / 128, 256, 0, stream>>>(x, W1, dinv, bufA, N);
    spmm_relu<128><<<(N + 3) / 4, 256, 0, stream>>>(bufA, rowptr, csr, dinv, b1, bufB, N);
    // layer 2
    gemm_scale<8, 1, 128, 64, 128><<<(N + 127) / 128, 256, 0, stream>>>(bufB, W2, dinv, bufA, N);
    spmm_relu<64><<<(N + 3) / 4, 256, 0, stream>>>(bufA, rowptr, csr, dinv, b2, bufB, N);
    // head
    head_kernel<<<(N + 255) / 256, 256, 0, stream>>>(bufB, Wl, bl, out, N);
}

// Round 3
// 591.046 us; speedup vs baseline: 1.1272x; 1.1272x over previous
//
#include <hip/hip_runtime.h>

// ---------------------------------------------------------------------------
// GCN, bf16 data-path version:
//  CSR build (unchanged) ->
//  GEMM1 (MFMA bf16: x fp32 cvt-on-load @ W1t_bf16, *dinv) -> M1' bf16 [N,128]
//  SpMM1 (bf16 gather, fp32 acc, relu)                     -> h1  bf16 [N,128]
//  GEMM2 (MFMA bf16: h1 @ W2t_bf16, *dinv)                 -> M2' bf16 [N,64]
//  SpMM2 (bf16 gather, fp32 acc, relu)                     -> h2  fp32 [N,64]
//  head: log_softmax(h2@Wl+bl) fp32
// MFMA fragment layouts (gfx950, verified): A[m=l&15][k=(l>>4)*8+j],
// B[k=(l>>4)*8+j][n=l&15], C/D col=l&15 row=(l>>4)*4+reg.
// ---------------------------------------------------------------------------

typedef unsigned short ushort_t;
typedef unsigned int uint_t;
typedef __attribute__((ext_vector_type(8))) short short8;
typedef __attribute__((ext_vector_type(4))) float floatx4;

static __device__ __forceinline__ ushort_t f2bf(float f) {
    union { float f; uint_t u; } c; c.f = f;
    return (ushort_t)((c.u + 0x8000u) >> 16);
}
static __device__ __forceinline__ float bf2f(ushort_t h) {
    union { uint_t u; float f; } c; c.u = ((uint_t)h) << 16;
    return c.f;
}
static __device__ __forceinline__ float2 up2(uint_t p) {
    union { uint_t u; float f; } lo, hi;
    lo.u = p << 16; hi.u = p & 0xffff0000u;
    return make_float2(lo.f, hi.f);
}

// ------------------------------ CSR build ----------------------------------

__global__ void deg_kernel(const int* __restrict__ dst, int* __restrict__ cnt,
                           int E, int n) {
    int stride = gridDim.x * blockDim.x;
    for (int e = blockIdx.x * blockDim.x + threadIdx.x; e < E; e += stride) {
        int d = dst[e];
        if (d >= 0 && d < n) atomicAdd(&cnt[d], 1);
    }
}

__global__ void dinv_kernel(const int* __restrict__ cnt, float* __restrict__ dinv, int n) {
    int v = blockIdx.x * blockDim.x + threadIdx.x;
    if (v < n) dinv[v] = rsqrtf((float)(cnt[v] + 1));
}

__global__ void scan_block(const int* __restrict__ cnt, int* __restrict__ rowptr,
                           int* __restrict__ bsums, int n) {
    __shared__ int s[256];
    int i = blockIdx.x * 256 + threadIdx.x;
    int v = (i < n) ? cnt[i] : 0;
    s[threadIdx.x] = v;
    __syncthreads();
    for (int off = 1; off < 256; off <<= 1) {
        int t = (threadIdx.x >= off) ? s[threadIdx.x - off] : 0;
        __syncthreads();
        s[threadIdx.x] += t;
        __syncthreads();
    }
    if (i < n) rowptr[i] = s[threadIdx.x] - v;
    if (threadIdx.x == 255) bsums[blockIdx.x] = s[255];
}

__global__ void scan_tops(const int* __restrict__ bsums, int* __restrict__ boffs, int nb) {
    __shared__ int s[512];
    int v = (threadIdx.x < nb) ? bsums[threadIdx.x] : 0;
    s[threadIdx.x] = v;
    __syncthreads();
    for (int off = 1; off < 512; off <<= 1) {
        int t = (threadIdx.x >= off) ? s[threadIdx.x - off] : 0;
        __syncthreads();
        s[threadIdx.x] += t;
        __syncthreads();
    }
    if (threadIdx.x < nb) boffs[threadIdx.x] = s[threadIdx.x] - v;
}

__global__ void finalize_rowptr(int* __restrict__ rowptr, const int* __restrict__ boffs,
                                int n, int E) {
    int i = blockIdx.x * 256 + threadIdx.x;
    if (i < n) rowptr[i] += boffs[blockIdx.x];
    if (i == 0) rowptr[n] = E;
}

__global__ void scatter_kernel(const int* __restrict__ src, const int* __restrict__ dst,
                               const int* __restrict__ rowptr, int* __restrict__ cur,
                               int* __restrict__ csr, int E, int n) {
    int stride = gridDim.x * blockDim.x;
    for (int e = blockIdx.x * blockDim.x + threadIdx.x; e < E; e += stride) {
        int d = dst[e];
        int s = src[e];
        if (d >= 0 && d < n && s >= 0 && s < n) {
            int p = atomicAdd(&cur[d], 1);
            csr[rowptr[d] + p] = s;
        }
    }
}

// --------------------- weight transpose + bf16 convert ---------------------
// Wt[n][k] = bf16(W[k][n]);  W is [K,Nn] row-major.
__global__ void wcvt_kernel(const float* __restrict__ W, ushort_t* __restrict__ Wt,
                            int K, int Nn) {
    int i = blockIdx.x * 256 + threadIdx.x;
    if (i < K * Nn) {
        int k = i / Nn, n = i % Nn;
        Wt[n * K + k] = f2bf(W[i]);
    }
}

// ------------------------------ MFMA GEMM ----------------------------------
// out[m][n] = bf16( dinv[m] * sum_k A[m][k]*Bt[n][k] )
// Block = 256 thr = 4 waves; block tile 64(M) x NOUT(N); wave covers NT n-tiles.
template<int K, int NOUT, int NT, bool AFP32>
__global__ __launch_bounds__(256) void gemm_mfma(
    const void* __restrict__ Av, const ushort_t* __restrict__ Bt,
    const float* __restrict__ dinv, ushort_t* __restrict__ out, int M) {
    const int l = threadIdx.x & 63;
    const int wave = threadIdx.x >> 6;
    const int lrow = l & 15;
    const int lk8 = (l >> 4) * 8;
    const int m0 = blockIdx.x * 64;
    const int n0w = wave * (NT * 16);

    floatx4 acc[4][NT];
    #pragma unroll
    for (int mt = 0; mt < 4; mt++)
        #pragma unroll
        for (int nt = 0; nt < NT; nt++)
            acc[mt][nt] = (floatx4){0.f, 0.f, 0.f, 0.f};

    const float*    Af = (const float*)Av;
    const ushort_t* Ab = (const ushort_t*)Av;

    int rows[4];
    #pragma unroll
    for (int mt = 0; mt < 4; mt++) {
        int r = m0 + mt * 16 + lrow;
        rows[mt] = (r < M) ? r : (M - 1);
    }

    for (int k0 = 0; k0 < K; k0 += 32) {
        short8 afr[4];
        #pragma unroll
        for (int mt = 0; mt < 4; mt++) {
            if (AFP32) {
                const float* ap = Af + (size_t)rows[mt] * K + k0 + lk8;
                float4 u = *(const float4*)ap;
                float4 v = *(const float4*)(ap + 4);
                short8 t;
                t[0] = (short)f2bf(u.x); t[1] = (short)f2bf(u.y);
                t[2] = (short)f2bf(u.z); t[3] = (short)f2bf(u.w);
                t[4] = (short)f2bf(v.x); t[5] = (short)f2bf(v.y);
                t[6] = (short)f2bf(v.z); t[7] = (short)f2bf(v.w);
                afr[mt] = t;
            } else {
                afr[mt] = *(const short8*)(Ab + (size_t)rows[mt] * K + k0 + lk8);
            }
        }
        short8 bfr[NT];
        #pragma unroll
        for (int nt = 0; nt < NT; nt++) {
            int n = n0w + nt * 16 + lrow;
            bfr[nt] = *(const short8*)(Bt + (size_t)n * K + k0 + lk8);
        }
        #pragma unroll
        for (int mt = 0; mt < 4; mt++)
            #pragma unroll
            for (int nt = 0; nt < NT; nt++)
                acc[mt][nt] = __builtin_amdgcn_mfma_f32_16x16x32_bf16(
                    afr[mt], bfr[nt], acc[mt][nt], 0, 0, 0);
    }

    const int r0 = (l >> 4) * 4;
    #pragma unroll
    for (int mt = 0; mt < 4; mt++) {
        int mbase = m0 + mt * 16 + r0;
        float4 dv = *(const float4*)&dinv[mbase];   // dinv padded past N
        float d[4] = {dv.x, dv.y, dv.z, dv.w};
        #pragma unroll
        for (int i = 0; i < 4; i++) {
            int m = mbase + i;
            if (m < M) {
                #pragma unroll
                for (int nt = 0; nt < NT; nt++)
                    out[(size_t)m * NOUT + n0w + nt * 16 + lrow] =
                        f2bf(acc[mt][nt][i] * d[i]);
            }
        }
    }
}

// ------------------------------ SpMM ---------------------------------------
// F=128, bf16 in, bf16 out: wave per node, lane handles 2 features.
__global__ __launch_bounds__(256) void spmm_relu128(
    const ushort_t* __restrict__ Mm, const int* __restrict__ rowptr,
    const int* __restrict__ csr, const float* __restrict__ dinv,
    const float* __restrict__ bias, ushort_t* __restrict__ out, int n) {
    int v = (blockIdx.x * 256 + threadIdx.x) >> 6;
    int lane = threadIdx.x & 63;
    if (v >= n) return;
    int jb = rowptr[v], je = rowptr[v + 1];
    float2 acc0 = up2(*(const uint_t*)(Mm + (size_t)v * 128 + lane * 2));  // self
    float2 acc1 = make_float2(0.f, 0.f);
    int j = jb;
    for (; j + 1 < je; j += 2) {
        int s0 = csr[j], s1 = csr[j + 1];
        float2 m0 = up2(*(const uint_t*)(Mm + (size_t)s0 * 128 + lane * 2));
        float2 m1 = up2(*(const uint_t*)(Mm + (size_t)s1 * 128 + lane * 2));
        acc0.x += m0.x; acc0.y += m0.y;
        acc1.x += m1.x; acc1.y += m1.y;
    }
    if (j < je) {
        float2 m0 = up2(*(const uint_t*)(Mm + (size_t)csr[j] * 128 + lane * 2));
        acc0.x += m0.x; acc0.y += m0.y;
    }
    float d = dinv[v];
    float2 bv = *(const float2*)&bias[lane * 2];
    float rx = fmaxf(d * (acc0.x + acc1.x) + bv.x, 0.f);
    float ry = fmaxf(d * (acc0.y + acc1.y) + bv.y, 0.f);
    uint_t packed = ((uint_t)f2bf(ry) << 16) | (uint_t)f2bf(rx);
    *(uint_t*)(out + (size_t)v * 128 + lane * 2) = packed;
}

// F=64, bf16 in, fp32 out: wave per node, lane handles 1 feature.
__global__ __launch_bounds__(256) void spmm_relu64(
    const ushort_t* __restrict__ Mm, const int* __restrict__ rowptr,
    const int* __restrict__ csr, const float* __restrict__ dinv,
    const float* __restrict__ bias, float* __restrict__ out, int n) {
    int v = (blockIdx.x * 256 + threadIdx.x) >> 6;
    int lane = threadIdx.x & 63;
    if (v >= n) return;
    int jb = rowptr[v], je = rowptr[v + 1];
    float acc0 = bf2f(Mm[(size_t)v * 64 + lane]);   // self
    float acc1 = 0.f;
    int j = jb;
    for (; j + 1 < je; j += 2) {
        int s0 = csr[j], s1 = csr[j + 1];
        acc0 += bf2f(Mm[(size_t)s0 * 64 + lane]);
        acc1 += bf2f(Mm[(size_t)s1 * 64 + lane]);
    }
    if (j < je) acc0 += bf2f(Mm[(size_t)csr[j] * 64 + lane]);
    float r = fmaxf(dinv[v] * (acc0 + acc1) + bias[lane], 0.f);
    out[(size_t)v * 64 + lane] = r;
}

// ------------------------------ head ---------------------------------------
__global__ __launch_bounds__(256) void head_kernel(
    const float* __restrict__ h2, const float* __restrict__ Wl,
    const float* __restrict__ bl, float* __restrict__ out, int n) {
    __shared__ float Ws[64 * 10];
    __shared__ float bs[10];
    for (int i = threadIdx.x; i < 640; i += 256) Ws[i] = Wl[i];
    if (threadIdx.x < 10) bs[threadIdx.x] = bl[threadIdx.x];
    __syncthreads();
    int v = blockIdx.x * 256 + threadIdx.x;
    if (v >= n) return;
    float acc[10];
    #pragma unroll
    for (int c = 0; c < 10; c++) acc[c] = bs[c];
    const float* hrow = &h2[(size_t)v * 64];
    #pragma unroll
    for (int k0 = 0; k0 < 64; k0 += 4) {
        float4 h = *(const float4*)&hrow[k0];
        float hv[4] = {h.x, h.y, h.z, h.w};
        #pragma unroll
        for (int kk = 0; kk < 4; kk++)
            #pragma unroll
            for (int c = 0; c < 10; c++)
                acc[c] += hv[kk] * Ws[(k0 + kk) * 10 + c];
    }
    float m = acc[0];
    #pragma unroll
    for (int c = 1; c < 10; c++) m = fmaxf(m, acc[c]);
    float s = 0.f;
    #pragma unroll
    for (int c = 0; c < 10; c++) s += expf(acc[c] - m);
    float lse = logf(s);
    #pragma unroll
    for (int c = 0; c < 10; c++) out[(size_t)v * 10 + c] = acc[c] - m - lse;
}

// ------------------------------ launch -------------------------------------
extern "C" void kernel_launch(void* const* d_in, const int* in_sizes, int n_in,
                              void* d_out, int out_size, void* d_ws, size_t ws_size,
                              hipStream_t stream) {
    const float* x   = (const float*)d_in[0];
    const int*   ei  = (const int*)d_in[1];      // int32 (JAX x64 disabled)
    const float* W1  = (const float*)d_in[2];
    const float* b1  = (const float*)d_in[3];
    const float* W2  = (const float*)d_in[4];
    const float* b2  = (const float*)d_in[5];
    const float* Wl  = (const float*)d_in[6];
    const float* bl  = (const float*)d_in[7];
    float*       out = (float*)d_out;

    const int N = in_sizes[0] / 256;   // 100000
    const int E = in_sizes[1] / 2;     // 1600000
    const int* srcI = ei;
    const int* dstI = ei + E;

    char* ws = (char*)d_ws;
    size_t off = 0;
    auto alloc = [&](size_t bytes) -> void* {
        void* p = ws + off;
        off = (off + bytes + 255) & ~(size_t)255;
        return p;
    };
    int*      cnt    = (int*)alloc((size_t)N * 4);
    int*      cur    = (int*)alloc((size_t)N * 4);
    int*      rowptr = (int*)alloc((size_t)(N + 1) * 4);
    float*    dinv   = (float*)alloc((size_t)(N + 64) * 4);   // padded for float4 epilogue reads
    int*      csr    = (int*)alloc((size_t)E * 4);
    int*      bsums  = (int*)alloc(512 * 4);
    int*      boffs  = (int*)alloc(512 * 4);
    ushort_t* W1t    = (ushort_t*)alloc((size_t)128 * 256 * 2);
    ushort_t* W2t    = (ushort_t*)alloc((size_t)64 * 128 * 2);
    ushort_t* bufA   = (ushort_t*)alloc((size_t)N * 128 * 2); // M1' / M2' (bf16)
    char*     bufB   = (char*)alloc((size_t)N * 128 * 2 > (size_t)N * 64 * 4
                                    ? (size_t)N * 128 * 2 : (size_t)N * 64 * 4);
    ushort_t* h1     = (ushort_t*)bufB;                        // bf16 [N,128]
    float*    h2     = (float*)bufB;                           // fp32 [N,64]

    hipMemsetAsync(cnt, 0, (size_t)N * 4, stream);
    hipMemsetAsync(cur, 0, (size_t)N * 4, stream);

    const int nb = (N + 255) / 256;  // 391 <= 512
    deg_kernel<<<1024, 256, 0, stream>>>(dstI, cnt, E, N);
    dinv_kernel<<<(N + 255) / 256, 256, 0, stream>>>(cnt, dinv, N);
    scan_block<<<nb, 256, 0, stream>>>(cnt, rowptr, bsums, N);
    scan_tops<<<1, 512, 0, stream>>>(bsums, boffs, nb);
    finalize_rowptr<<<nb, 256, 0, stream>>>(rowptr, boffs, N, E);
    scatter_kernel<<<1024, 256, 0, stream>>>(srcI, dstI, rowptr, cur, csr, E, N);

    wcvt_kernel<<<(256 * 128 + 255) / 256, 256, 0, stream>>>(W1, W1t, 256, 128);
    wcvt_kernel<<<(128 * 64 + 255) / 256, 256, 0, stream>>>(W2, W2t, 128, 64);

    const int gblk = (N + 63) / 64;
    // layer 1
    gemm_mfma<256, 128, 2, true><<<gblk, 256, 0, stream>>>(x, W1t, dinv, bufA, N);
    spmm_relu128<<<(N + 3) / 4, 256, 0, stream>>>(bufA, rowptr, csr, dinv, b1, h1, N);
    // layer 2
    gemm_mfma<128, 64, 1, false><<<gblk, 256, 0, stream>>>(h1, W2t, dinv, bufA, N);
    spmm_relu64<<<(N + 3) / 4, 256, 0, stream>>>(bufA, rowptr, csr, dinv, b2, h2, N);
    // head
    head_kernel<<<(N + 255) / 256, 256, 0, stream>>>(h2, Wl, bl, out, N);
}

// Round 4
// 539.551 us; speedup vs baseline: 1.2348x; 1.0954x over previous
//
#include <hip/hip_runtime.h>

// ---------------------------------------------------------------------------
// GCN, bf16 data-path, pipelined-gather version:
//  CSR build -> GEMM1 (MFMA bf16) -> SpMM1 (pipelined gather) ->
//  GEMM2 (MFMA bf16) -> SpMM2+head fused (gather + Wl butterfly + log_softmax)
// SpMM gathers: one coalesced index load per <=64 neighbors, __shfl broadcast,
// 8 independent gathers in flight (breaks index->gather latency chain).
// ---------------------------------------------------------------------------

typedef unsigned short ushort_t;
typedef unsigned int uint_t;
typedef __attribute__((ext_vector_type(8))) short short8;
typedef __attribute__((ext_vector_type(4))) float floatx4;

static __device__ __forceinline__ ushort_t f2bf(float f) {
    union { float f; uint_t u; } c; c.f = f;
    return (ushort_t)((c.u + 0x8000u) >> 16);
}
static __device__ __forceinline__ float bf2f(ushort_t h) {
    union { uint_t u; float f; } c; c.u = ((uint_t)h) << 16;
    return c.f;
}
static __device__ __forceinline__ float2 up2(uint_t p) {
    union { uint_t u; float f; } lo, hi;
    lo.u = p << 16; hi.u = p & 0xffff0000u;
    return make_float2(lo.f, hi.f);
}

// ------------------------------ CSR build ----------------------------------

__global__ void deg_kernel(const int* __restrict__ dst, int* __restrict__ cnt,
                           int E, int n) {
    int stride = gridDim.x * blockDim.x;
    for (int e = blockIdx.x * blockDim.x + threadIdx.x; e < E; e += stride) {
        int d = dst[e];
        if (d >= 0 && d < n) atomicAdd(&cnt[d], 1);
    }
}

// scan + dinv fused (reads cnt anyway)
__global__ void scan_block(const int* __restrict__ cnt, int* __restrict__ rowptr,
                           int* __restrict__ bsums, float* __restrict__ dinv, int n) {
    __shared__ int s[256];
    int i = blockIdx.x * 256 + threadIdx.x;
    int v = (i < n) ? cnt[i] : 0;
    if (i < n) dinv[i] = rsqrtf((float)(v + 1));   // +1 self loop
    s[threadIdx.x] = v;
    __syncthreads();
    for (int off = 1; off < 256; off <<= 1) {
        int t = (threadIdx.x >= off) ? s[threadIdx.x - off] : 0;
        __syncthreads();
        s[threadIdx.x] += t;
        __syncthreads();
    }
    if (i < n) rowptr[i] = s[threadIdx.x] - v;
    if (threadIdx.x == 255) bsums[blockIdx.x] = s[255];
}

__global__ void scan_tops(const int* __restrict__ bsums, int* __restrict__ boffs, int nb) {
    __shared__ int s[512];
    int v = (threadIdx.x < nb) ? bsums[threadIdx.x] : 0;
    s[threadIdx.x] = v;
    __syncthreads();
    for (int off = 1; off < 512; off <<= 1) {
        int t = (threadIdx.x >= off) ? s[threadIdx.x - off] : 0;
        __syncthreads();
        s[threadIdx.x] += t;
        __syncthreads();
    }
    if (threadIdx.x < nb) boffs[threadIdx.x] = s[threadIdx.x] - v;
}

__global__ void finalize_rowptr(int* __restrict__ rowptr, const int* __restrict__ boffs,
                                int n, int E) {
    int i = blockIdx.x * 256 + threadIdx.x;
    if (i < n) rowptr[i] += boffs[blockIdx.x];
    if (i == 0) rowptr[n] = E;
}

__global__ void scatter_kernel(const int* __restrict__ src, const int* __restrict__ dst,
                               const int* __restrict__ rowptr, int* __restrict__ cur,
                               int* __restrict__ csr, int E, int n) {
    int stride = gridDim.x * blockDim.x;
    for (int e = blockIdx.x * blockDim.x + threadIdx.x; e < E; e += stride) {
        int d = dst[e];
        int s = src[e];
        if (d >= 0 && d < n && s >= 0 && s < n) {
            int p = atomicAdd(&cur[d], 1);
            csr[rowptr[d] + p] = s;
        }
    }
}

// --------------------- weight transpose + bf16 convert ---------------------
__global__ void wcvt_kernel(const float* __restrict__ W, ushort_t* __restrict__ Wt,
                            int K, int Nn) {
    int i = blockIdx.x * 256 + threadIdx.x;
    if (i < K * Nn) {
        int k = i / Nn, n = i % Nn;
        Wt[n * K + k] = f2bf(W[i]);
    }
}

// ------------------------------ MFMA GEMM ----------------------------------
// out[m][n] = bf16( dinv[m] * sum_k A[m][k]*Bt[n][k] )
template<int K, int NOUT, int NT, bool AFP32>
__global__ __launch_bounds__(256) void gemm_mfma(
    const void* __restrict__ Av, const ushort_t* __restrict__ Bt,
    const float* __restrict__ dinv, ushort_t* __restrict__ out, int M) {
    const int l = threadIdx.x & 63;
    const int wave = threadIdx.x >> 6;
    const int lrow = l & 15;
    const int lk8 = (l >> 4) * 8;
    const int m0 = blockIdx.x * 64;
    const int n0w = wave * (NT * 16);

    floatx4 acc[4][NT];
    #pragma unroll
    for (int mt = 0; mt < 4; mt++)
        #pragma unroll
        for (int nt = 0; nt < NT; nt++)
            acc[mt][nt] = (floatx4){0.f, 0.f, 0.f, 0.f};

    const float*    Af = (const float*)Av;
    const ushort_t* Ab = (const ushort_t*)Av;

    int rows[4];
    #pragma unroll
    for (int mt = 0; mt < 4; mt++) {
        int r = m0 + mt * 16 + lrow;
        rows[mt] = (r < M) ? r : (M - 1);
    }

    for (int k0 = 0; k0 < K; k0 += 32) {
        short8 afr[4];
        #pragma unroll
        for (int mt = 0; mt < 4; mt++) {
            if (AFP32) {
                const float* ap = Af + (size_t)rows[mt] * K + k0 + lk8;
                float4 u = *(const float4*)ap;
                float4 v = *(const float4*)(ap + 4);
                short8 t;
                t[0] = (short)f2bf(u.x); t[1] = (short)f2bf(u.y);
                t[2] = (short)f2bf(u.z); t[3] = (short)f2bf(u.w);
                t[4] = (short)f2bf(v.x); t[5] = (short)f2bf(v.y);
                t[6] = (short)f2bf(v.z); t[7] = (short)f2bf(v.w);
                afr[mt] = t;
            } else {
                afr[mt] = *(const short8*)(Ab + (size_t)rows[mt] * K + k0 + lk8);
            }
        }
        short8 bfr[NT];
        #pragma unroll
        for (int nt = 0; nt < NT; nt++) {
            int n = n0w + nt * 16 + lrow;
            bfr[nt] = *(const short8*)(Bt + (size_t)n * K + k0 + lk8);
        }
        #pragma unroll
        for (int mt = 0; mt < 4; mt++)
            #pragma unroll
            for (int nt = 0; nt < NT; nt++)
                acc[mt][nt] = __builtin_amdgcn_mfma_f32_16x16x32_bf16(
                    afr[mt], bfr[nt], acc[mt][nt], 0, 0, 0);
    }

    const int r0 = (l >> 4) * 4;
    #pragma unroll
    for (int mt = 0; mt < 4; mt++) {
        int mbase = m0 + mt * 16 + r0;
        float4 dv = *(const float4*)&dinv[mbase];   // dinv padded past N
        float d[4] = {dv.x, dv.y, dv.z, dv.w};
        #pragma unroll
        for (int i = 0; i < 4; i++) {
            int m = mbase + i;
            if (m < M) {
                #pragma unroll
                for (int nt = 0; nt < NT; nt++)
                    out[(size_t)m * NOUT + n0w + nt * 16 + lrow] =
                        f2bf(acc[mt][nt][i] * d[i]);
            }
        }
    }
}

// ------------------------------ SpMM 1 -------------------------------------
// F=128, bf16 in/out. Wave per node; coalesced index load + shfl broadcast +
// 8 gathers in flight.
__global__ __launch_bounds__(256) void spmm_relu128(
    const ushort_t* __restrict__ Mm, const int* __restrict__ rowptr,
    const int* __restrict__ csr, const float* __restrict__ dinv,
    const float* __restrict__ bias, ushort_t* __restrict__ out, int n) {
    int v = (blockIdx.x * 256 + threadIdx.x) >> 6;
    int lane = threadIdx.x & 63;
    if (v >= n) return;
    int jb = rowptr[v], je = rowptr[v + 1];
    int cntn = je - jb;

    float2 accA = up2(*(const uint_t*)(Mm + (size_t)v * 128 + lane * 2));  // self
    float2 accB = make_float2(0.f, 0.f);

    for (int base = 0; base < cntn; base += 64) {
        int m = cntn - base; if (m > 64) m = 64;
        int idx = (base + lane < cntn) ? csr[jb + base + lane] : 0;
        int jj = 0;
        for (; jj + 8 <= m; jj += 8) {
            int sI[8];
            #pragma unroll
            for (int t = 0; t < 8; t++) sI[t] = __shfl(idx, jj + t);
            uint_t p[8];
            #pragma unroll
            for (int t = 0; t < 8; t++)
                p[t] = *(const uint_t*)(Mm + (size_t)sI[t] * 128 + lane * 2);
            #pragma unroll
            for (int t = 0; t < 8; t++) {
                float2 f = up2(p[t]);
                if (t & 1) { accB.x += f.x; accB.y += f.y; }
                else       { accA.x += f.x; accA.y += f.y; }
            }
        }
        for (; jj < m; jj++) {
            int s = __shfl(idx, jj);
            float2 f = up2(*(const uint_t*)(Mm + (size_t)s * 128 + lane * 2));
            accA.x += f.x; accA.y += f.y;
        }
    }
    float d = dinv[v];
    float2 bv = *(const float2*)&bias[lane * 2];
    float rx = fmaxf(d * (accA.x + accB.x) + bv.x, 0.f);
    float ry = fmaxf(d * (accA.y + accB.y) + bv.y, 0.f);
    uint_t packed = ((uint_t)f2bf(ry) << 16) | (uint_t)f2bf(rx);
    *(uint_t*)(out + (size_t)v * 128 + lane * 2) = packed;
}

// ------------------------- SpMM 2 + head fused -----------------------------
// F=64, bf16 in. h2[lane] = relu(dinv*(sum)+b2[lane]); then
// logits[c] = butterfly_sum(h2[lane]*Wl[lane][c]) + bl[c]; log_softmax; write.
__global__ __launch_bounds__(256) void spmm_head64(
    const ushort_t* __restrict__ Mm, const int* __restrict__ rowptr,
    const int* __restrict__ csr, const float* __restrict__ dinv,
    const float* __restrict__ bias, const float* __restrict__ Wl,
    const float* __restrict__ bl, float* __restrict__ out, int n) {
    int v = (blockIdx.x * 256 + threadIdx.x) >> 6;
    int lane = threadIdx.x & 63;
    if (v >= n) return;
    int jb = rowptr[v], je = rowptr[v + 1];
    int cntn = je - jb;

    float accA = bf2f(Mm[(size_t)v * 64 + lane]);   // self
    float accB = 0.f;

    for (int base = 0; base < cntn; base += 64) {
        int m = cntn - base; if (m > 64) m = 64;
        int idx = (base + lane < cntn) ? csr[jb + base + lane] : 0;
        int jj = 0;
        for (; jj + 8 <= m; jj += 8) {
            int sI[8];
            #pragma unroll
            for (int t = 0; t < 8; t++) sI[t] = __shfl(idx, jj + t);
            ushort_t p[8];
            #pragma unroll
            for (int t = 0; t < 8; t++)
                p[t] = Mm[(size_t)sI[t] * 64 + lane];
            #pragma unroll
            for (int t = 0; t < 8; t++) {
                if (t & 1) accB += bf2f(p[t]);
                else       accA += bf2f(p[t]);
            }
        }
        for (; jj < m; jj++) {
            int s = __shfl(idx, jj);
            accA += bf2f(Mm[(size_t)s * 64 + lane]);
        }
    }
    float h = fmaxf(dinv[v] * (accA + accB) + bias[lane], 0.f);

    // head: logits[c] = sum_lane h*Wl[lane*10+c] (+bl)
    float t[10];
    {
        const float* wr = &Wl[lane * 10];
        #pragma unroll
        for (int c = 0; c < 10; c++) t[c] = h * wr[c];
    }
    #pragma unroll
    for (int off = 32; off >= 1; off >>= 1)
        #pragma unroll
        for (int c = 0; c < 10; c++)
            t[c] += __shfl_xor(t[c], off);
    #pragma unroll
    for (int c = 0; c < 10; c++) t[c] += bl[c];

    float mx = t[0];
    #pragma unroll
    for (int c = 1; c < 10; c++) mx = fmaxf(mx, t[c]);
    float s = 0.f;
    #pragma unroll
    for (int c = 0; c < 10; c++) s += expf(t[c] - mx);
    float lse = logf(s) + mx;

    float val = t[0];
    #pragma unroll
    for (int c = 1; c < 10; c++) val = (lane == c) ? t[c] : val;
    if (lane < 10) out[(size_t)v * 10 + lane] = val - lse;
}

// ------------------------------ launch -------------------------------------
extern "C" void kernel_launch(void* const* d_in, const int* in_sizes, int n_in,
                              void* d_out, int out_size, void* d_ws, size_t ws_size,
                              hipStream_t stream) {
    const float* x   = (const float*)d_in[0];
    const int*   ei  = (const int*)d_in[1];      // int32 (JAX x64 disabled)
    const float* W1  = (const float*)d_in[2];
    const float* b1  = (const float*)d_in[3];
    const float* W2  = (const float*)d_in[4];
    const float* b2  = (const float*)d_in[5];
    const float* Wl  = (const float*)d_in[6];
    const float* bl  = (const float*)d_in[7];
    float*       out = (float*)d_out;

    const int N = in_sizes[0] / 256;   // 100000
    const int E = in_sizes[1] / 2;     // 1600000
    const int* srcI = ei;
    const int* dstI = ei + E;

    char* ws = (char*)d_ws;
    size_t off = 0;
    auto alloc = [&](size_t bytes) -> void* {
        void* p = ws + off;
        off = (off + bytes + 255) & ~(size_t)255;
        return p;
    };
    int*      cnt    = (int*)alloc((size_t)N * 4);
    int*      cur    = (int*)alloc((size_t)N * 4);
    int*      rowptr = (int*)alloc((size_t)(N + 1) * 4);
    float*    dinv   = (float*)alloc((size_t)(N + 64) * 4);   // padded for float4 reads
    int*      csr    = (int*)alloc((size_t)E * 4);
    int*      bsums  = (int*)alloc(512 * 4);
    int*      boffs  = (int*)alloc(512 * 4);
    ushort_t* W1t    = (ushort_t*)alloc((size_t)128 * 256 * 2);
    ushort_t* W2t    = (ushort_t*)alloc((size_t)64 * 128 * 2);
    ushort_t* bufA   = (ushort_t*)alloc((size_t)N * 128 * 2); // M1' / M2' (bf16)
    ushort_t* h1     = (ushort_t*)alloc((size_t)N * 128 * 2); // h1 (bf16)

    hipMemsetAsync(cnt, 0, (size_t)N * 4, stream);
    hipMemsetAsync(cur, 0, (size_t)N * 4, stream);

    const int nb = (N + 255) / 256;  // 391 <= 512
    deg_kernel<<<1024, 256, 0, stream>>>(dstI, cnt, E, N);
    scan_block<<<nb, 256, 0, stream>>>(cnt, rowptr, bsums, dinv, N);
    scan_tops<<<1, 512, 0, stream>>>(bsums, boffs, nb);
    finalize_rowptr<<<nb, 256, 0, stream>>>(rowptr, boffs, N, E);
    scatter_kernel<<<1024, 256, 0, stream>>>(srcI, dstI, rowptr, cur, csr, E, N);

    wcvt_kernel<<<(256 * 128 + 255) / 256, 256, 0, stream>>>(W1, W1t, 256, 128);
    wcvt_kernel<<<(128 * 64 + 255) / 256, 256, 0, stream>>>(W2, W2t, 128, 64);

    const int gblk = (N + 63) / 64;
    // layer 1
    gemm_mfma<256, 128, 2, true><<<gblk, 256, 0, stream>>>(x, W1t, dinv, bufA, N);
    spmm_relu128<<<(N + 3) / 4, 256, 0, stream>>>(bufA, rowptr, csr, dinv, b1, h1, N);
    // layer 2
    gemm_mfma<128, 64, 1, false><<<gblk, 256, 0, stream>>>(h1, W2t, dinv, bufA, N);
    // spmm2 + head fused
    spmm_head64<<<(N + 3) / 4, 256, 0, stream>>>(bufA, rowptr, csr, dinv, b2, Wl, bl, out, N);
}

// Round 5
// 515.174 us; speedup vs baseline: 1.2932x; 1.0473x over previous
//
#include <hip/hip_runtime.h>

// ---------------------------------------------------------------------------
// GCN, bf16 data-path, pipelined-gather version (head un-fused):
//  CSR build -> GEMM1 (MFMA bf16) -> SpMM1 (pipelined gather) ->
//  GEMM2 (MFMA bf16) -> SpMM2 (pipelined gather, bf16 h2) ->
//  head (thread-per-node logits + log_softmax)
// Round-4 lesson: fusing the 10-class butterfly into wave-per-node SpMM made
// it VALU-bound (77% VALUBusy). Thread-per-node head is ~12us instead.
// ---------------------------------------------------------------------------

typedef unsigned short ushort_t;
typedef unsigned int uint_t;
typedef __attribute__((ext_vector_type(8))) short short8;
typedef __attribute__((ext_vector_type(4))) float floatx4;

static __device__ __forceinline__ ushort_t f2bf(float f) {
    union { float f; uint_t u; } c; c.f = f;
    return (ushort_t)((c.u + 0x8000u) >> 16);
}
static __device__ __forceinline__ float bf2f(ushort_t h) {
    union { uint_t u; float f; } c; c.u = ((uint_t)h) << 16;
    return c.f;
}
static __device__ __forceinline__ float2 up2(uint_t p) {
    union { uint_t u; float f; } lo, hi;
    lo.u = p << 16; hi.u = p & 0xffff0000u;
    return make_float2(lo.f, hi.f);
}

// ------------------------------ CSR build ----------------------------------

__global__ void deg_kernel(const int* __restrict__ dst, int* __restrict__ cnt,
                           int E, int n) {
    int stride = gridDim.x * blockDim.x;
    int E4 = E >> 2;
    const int4* d4 = (const int4*)dst;
    for (int i = blockIdx.x * blockDim.x + threadIdx.x; i < E4; i += stride) {
        int4 d = d4[i];
        if (d.x >= 0 && d.x < n) atomicAdd(&cnt[d.x], 1);
        if (d.y >= 0 && d.y < n) atomicAdd(&cnt[d.y], 1);
        if (d.z >= 0 && d.z < n) atomicAdd(&cnt[d.z], 1);
        if (d.w >= 0 && d.w < n) atomicAdd(&cnt[d.w], 1);
    }
    // tail
    int t = blockIdx.x * blockDim.x + threadIdx.x;
    int e = E4 * 4 + t;
    if (t < (E & 3) && e < E) {
        int d = dst[e];
        if (d >= 0 && d < n) atomicAdd(&cnt[d], 1);
    }
}

// scan + dinv fused (reads cnt anyway)
__global__ void scan_block(const int* __restrict__ cnt, int* __restrict__ rowptr,
                           int* __restrict__ bsums, float* __restrict__ dinv, int n) {
    __shared__ int s[256];
    int i = blockIdx.x * 256 + threadIdx.x;
    int v = (i < n) ? cnt[i] : 0;
    if (i < n) dinv[i] = rsqrtf((float)(v + 1));   // +1 self loop
    s[threadIdx.x] = v;
    __syncthreads();
    for (int off = 1; off < 256; off <<= 1) {
        int t = (threadIdx.x >= off) ? s[threadIdx.x - off] : 0;
        __syncthreads();
        s[threadIdx.x] += t;
        __syncthreads();
    }
    if (i < n) rowptr[i] = s[threadIdx.x] - v;
    if (threadIdx.x == 255) bsums[blockIdx.x] = s[255];
}

__global__ void scan_tops(const int* __restrict__ bsums, int* __restrict__ boffs, int nb) {
    __shared__ int s[512];
    int v = (threadIdx.x < nb) ? bsums[threadIdx.x] : 0;
    s[threadIdx.x] = v;
    __syncthreads();
    for (int off = 1; off < 512; off <<= 1) {
        int t = (threadIdx.x >= off) ? s[threadIdx.x - off] : 0;
        __syncthreads();
        s[threadIdx.x] += t;
        __syncthreads();
    }
    if (threadIdx.x < nb) boffs[threadIdx.x] = s[threadIdx.x] - v;
}

__global__ void finalize_rowptr(int* __restrict__ rowptr, const int* __restrict__ boffs,
                                int n, int E) {
    int i = blockIdx.x * 256 + threadIdx.x;
    if (i < n) rowptr[i] += boffs[blockIdx.x];
    if (i == 0) rowptr[n] = E;
}

__global__ void scatter_kernel(const int* __restrict__ src, const int* __restrict__ dst,
                               const int* __restrict__ rowptr, int* __restrict__ cur,
                               int* __restrict__ csr, int E, int n) {
    int stride = gridDim.x * blockDim.x;
    for (int e = blockIdx.x * blockDim.x + threadIdx.x; e < E; e += stride) {
        int d = dst[e];
        int s = src[e];
        if (d >= 0 && d < n && s >= 0 && s < n) {
            int p = atomicAdd(&cur[d], 1);
            csr[rowptr[d] + p] = s;
        }
    }
}

// --------------- both weight transposes + bf16 convert, one launch ---------
__global__ void wcvt2_kernel(const float* __restrict__ W1, const float* __restrict__ W2,
                             ushort_t* __restrict__ W1t, ushort_t* __restrict__ W2t) {
    int i = blockIdx.x * 256 + threadIdx.x;
    if (i < 256 * 128) {
        int k = i / 128, n = i % 128;
        W1t[n * 256 + k] = f2bf(W1[i]);
    }
    int j = i - 256 * 128;
    if (j >= 0 && j < 128 * 64) {
        int k = j / 64, n = j % 64;
        W2t[n * 128 + k] = f2bf(W2[j]);
    }
}

// ------------------------------ MFMA GEMM ----------------------------------
// out[m][n] = bf16( dinv[m] * sum_k A[m][k]*Bt[n][k] )
template<int K, int NOUT, int NT, bool AFP32>
__global__ __launch_bounds__(256) void gemm_mfma(
    const void* __restrict__ Av, const ushort_t* __restrict__ Bt,
    const float* __restrict__ dinv, ushort_t* __restrict__ out, int M) {
    const int l = threadIdx.x & 63;
    const int wave = threadIdx.x >> 6;
    const int lrow = l & 15;
    const int lk8 = (l >> 4) * 8;
    const int m0 = blockIdx.x * 64;
    const int n0w = wave * (NT * 16);

    floatx4 acc[4][NT];
    #pragma unroll
    for (int mt = 0; mt < 4; mt++)
        #pragma unroll
        for (int nt = 0; nt < NT; nt++)
            acc[mt][nt] = (floatx4){0.f, 0.f, 0.f, 0.f};

    const float*    Af = (const float*)Av;
    const ushort_t* Ab = (const ushort_t*)Av;

    int rows[4];
    #pragma unroll
    for (int mt = 0; mt < 4; mt++) {
        int r = m0 + mt * 16 + lrow;
        rows[mt] = (r < M) ? r : (M - 1);
    }

    for (int k0 = 0; k0 < K; k0 += 32) {
        short8 afr[4];
        #pragma unroll
        for (int mt = 0; mt < 4; mt++) {
            if (AFP32) {
                const float* ap = Af + (size_t)rows[mt] * K + k0 + lk8;
                float4 u = *(const float4*)ap;
                float4 v = *(const float4*)(ap + 4);
                short8 t;
                t[0] = (short)f2bf(u.x); t[1] = (short)f2bf(u.y);
                t[2] = (short)f2bf(u.z); t[3] = (short)f2bf(u.w);
                t[4] = (short)f2bf(v.x); t[5] = (short)f2bf(v.y);
                t[6] = (short)f2bf(v.z); t[7] = (short)f2bf(v.w);
                afr[mt] = t;
            } else {
                afr[mt] = *(const short8*)(Ab + (size_t)rows[mt] * K + k0 + lk8);
            }
        }
        short8 bfr[NT];
        #pragma unroll
        for (int nt = 0; nt < NT; nt++) {
            int n = n0w + nt * 16 + lrow;
            bfr[nt] = *(const short8*)(Bt + (size_t)n * K + k0 + lk8);
        }
        #pragma unroll
        for (int mt = 0; mt < 4; mt++)
            #pragma unroll
            for (int nt = 0; nt < NT; nt++)
                acc[mt][nt] = __builtin_amdgcn_mfma_f32_16x16x32_bf16(
                    afr[mt], bfr[nt], acc[mt][nt], 0, 0, 0);
    }

    const int r0 = (l >> 4) * 4;
    #pragma unroll
    for (int mt = 0; mt < 4; mt++) {
        int mbase = m0 + mt * 16 + r0;
        float4 dv = *(const float4*)&dinv[mbase];   // dinv padded past N
        float d[4] = {dv.x, dv.y, dv.z, dv.w};
        #pragma unroll
        for (int i = 0; i < 4; i++) {
            int m = mbase + i;
            if (m < M) {
                #pragma unroll
                for (int nt = 0; nt < NT; nt++)
                    out[(size_t)m * NOUT + n0w + nt * 16 + lrow] =
                        f2bf(acc[mt][nt][i] * d[i]);
            }
        }
    }
}

// ------------------------------ SpMM 1 -------------------------------------
// F=128, bf16 in/out. Wave per node; coalesced index load + shfl broadcast +
// 8 gathers in flight.
__global__ __launch_bounds__(256) void spmm_relu128(
    const ushort_t* __restrict__ Mm, const int* __restrict__ rowptr,
    const int* __restrict__ csr, const float* __restrict__ dinv,
    const float* __restrict__ bias, ushort_t* __restrict__ out, int n) {
    int v = (blockIdx.x * 256 + threadIdx.x) >> 6;
    int lane = threadIdx.x & 63;
    if (v >= n) return;
    int jb = rowptr[v], je = rowptr[v + 1];
    int cntn = je - jb;

    float2 accA = up2(*(const uint_t*)(Mm + (size_t)v * 128 + lane * 2));  // self
    float2 accB = make_float2(0.f, 0.f);

    for (int base = 0; base < cntn; base += 64) {
        int m = cntn - base; if (m > 64) m = 64;
        int idx = (base + lane < cntn) ? csr[jb + base + lane] : 0;
        int jj = 0;
        for (; jj + 8 <= m; jj += 8) {
            int sI[8];
            #pragma unroll
            for (int t = 0; t < 8; t++) sI[t] = __shfl(idx, jj + t);
            uint_t p[8];
            #pragma unroll
            for (int t = 0; t < 8; t++)
                p[t] = *(const uint_t*)(Mm + (size_t)sI[t] * 128 + lane * 2);
            #pragma unroll
            for (int t = 0; t < 8; t++) {
                float2 f = up2(p[t]);
                if (t & 1) { accB.x += f.x; accB.y += f.y; }
                else       { accA.x += f.x; accA.y += f.y; }
            }
        }
        for (; jj < m; jj++) {
            int s = __shfl(idx, jj);
            float2 f = up2(*(const uint_t*)(Mm + (size_t)s * 128 + lane * 2));
            accA.x += f.x; accA.y += f.y;
        }
    }
    float d = dinv[v];
    float2 bv = *(const float2*)&bias[lane * 2];
    float rx = fmaxf(d * (accA.x + accB.x) + bv.x, 0.f);
    float ry = fmaxf(d * (accA.y + accB.y) + bv.y, 0.f);
    uint_t packed = ((uint_t)f2bf(ry) << 16) | (uint_t)f2bf(rx);
    *(uint_t*)(out + (size_t)v * 128 + lane * 2) = packed;
}

// ------------------------------ SpMM 2 -------------------------------------
// F=64, bf16 in, bf16 out. Wave per node; pipelined gather, NO head.
__global__ __launch_bounds__(256) void spmm_relu64(
    const ushort_t* __restrict__ Mm, const int* __restrict__ rowptr,
    const int* __restrict__ csr, const float* __restrict__ dinv,
    const float* __restrict__ bias, ushort_t* __restrict__ out, int n) {
    int v = (blockIdx.x * 256 + threadIdx.x) >> 6;
    int lane = threadIdx.x & 63;
    if (v >= n) return;
    int jb = rowptr[v], je = rowptr[v + 1];
    int cntn = je - jb;

    float accA = bf2f(Mm[(size_t)v * 64 + lane]);   // self
    float accB = 0.f;

    for (int base = 0; base < cntn; base += 64) {
        int m = cntn - base; if (m > 64) m = 64;
        int idx = (base + lane < cntn) ? csr[jb + base + lane] : 0;
        int jj = 0;
        for (; jj + 8 <= m; jj += 8) {
            int sI[8];
            #pragma unroll
            for (int t = 0; t < 8; t++) sI[t] = __shfl(idx, jj + t);
            ushort_t p[8];
            #pragma unroll
            for (int t = 0; t < 8; t++)
                p[t] = Mm[(size_t)sI[t] * 64 + lane];
            #pragma unroll
            for (int t = 0; t < 8; t++) {
                if (t & 1) accB += bf2f(p[t]);
                else       accA += bf2f(p[t]);
            }
        }
        for (; jj < m; jj++) {
            int s = __shfl(idx, jj);
            accA += bf2f(Mm[(size_t)s * 64 + lane]);
        }
    }
    float r = fmaxf(dinv[v] * (accA + accB) + bias[lane], 0.f);
    out[(size_t)v * 64 + lane] = f2bf(r);
}

// ------------------------------ head ---------------------------------------
// thread per node: logits = h2 @ Wl + bl (Wl in LDS, uniform broadcast reads),
// then log_softmax.
__global__ __launch_bounds__(256) void head_kernel(
    const ushort_t* __restrict__ h2, const float* __restrict__ Wl,
    const float* __restrict__ bl, float* __restrict__ out, int n) {
    __shared__ float Ws[64 * 10];
    __shared__ float bs[10];
    for (int i = threadIdx.x; i < 640; i += 256) Ws[i] = Wl[i];
    if (threadIdx.x < 10) bs[threadIdx.x] = bl[threadIdx.x];
    __syncthreads();
    int v = blockIdx.x * 256 + threadIdx.x;
    if (v >= n) return;
    float acc[10];
    #pragma unroll
    for (int c = 0; c < 10; c++) acc[c] = bs[c];
    const ushort_t* hrow = &h2[(size_t)v * 64];
    #pragma unroll
    for (int k0 = 0; k0 < 64; k0 += 8) {
        short8 hv = *(const short8*)&hrow[k0];
        #pragma unroll
        for (int kk = 0; kk < 8; kk++) {
            float hf = bf2f((ushort_t)hv[kk]);
            #pragma unroll
            for (int c = 0; c < 10; c++)
                acc[c] += hf * Ws[(k0 + kk) * 10 + c];
        }
    }
    float m = acc[0];
    #pragma unroll
    for (int c = 1; c < 10; c++) m = fmaxf(m, acc[c]);
    float s = 0.f;
    #pragma unroll
    for (int c = 0; c < 10; c++) s += expf(acc[c] - m);
    float lse = logf(s);
    #pragma unroll
    for (int c = 0; c < 10; c++) out[(size_t)v * 10 + c] = acc[c] - m - lse;
}

// ------------------------------ launch -------------------------------------
extern "C" void kernel_launch(void* const* d_in, const int* in_sizes, int n_in,
                              void* d_out, int out_size, void* d_ws, size_t ws_size,
                              hipStream_t stream) {
    const float* x   = (const float*)d_in[0];
    const int*   ei  = (const int*)d_in[1];      // int32 (JAX x64 disabled)
    const float* W1  = (const float*)d_in[2];
    const float* b1  = (const float*)d_in[3];
    const float* W2  = (const float*)d_in[4];
    const float* b2  = (const float*)d_in[5];
    const float* Wl  = (const float*)d_in[6];
    const float* bl  = (const float*)d_in[7];
    float*       out = (float*)d_out;

    const int N = in_sizes[0] / 256;   // 100000
    const int E = in_sizes[1] / 2;     // 1600000
    const int* srcI = ei;
    const int* dstI = ei + E;

    char* ws = (char*)d_ws;
    size_t off = 0;
    auto alloc = [&](size_t bytes) -> void* {
        void* p = ws + off;
        off = (off + bytes + 255) & ~(size_t)255;
        return p;
    };
    int*      cnt    = (int*)alloc((size_t)N * 4);
    int*      cur    = (int*)alloc((size_t)N * 4);
    int*      rowptr = (int*)alloc((size_t)(N + 1) * 4);
    float*    dinv   = (float*)alloc((size_t)(N + 64) * 4);   // padded for float4 reads
    int*      csr    = (int*)alloc((size_t)E * 4);
    int*      bsums  = (int*)alloc(512 * 4);
    int*      boffs  = (int*)alloc(512 * 4);
    ushort_t* W1t    = (ushort_t*)alloc((size_t)128 * 256 * 2);
    ushort_t* W2t    = (ushort_t*)alloc((size_t)64 * 128 * 2);
    ushort_t* bufA   = (ushort_t*)alloc((size_t)N * 128 * 2); // M1' / M2' (bf16)
    ushort_t* bufB   = (ushort_t*)alloc((size_t)N * 128 * 2); // h1 / h2 (bf16)

    hipMemsetAsync(cnt, 0, (size_t)N * 4, stream);
    hipMemsetAsync(cur, 0, (size_t)N * 4, stream);

    const int nb = (N + 255) / 256;  // 391 <= 512
    deg_kernel<<<1024, 256, 0, stream>>>(dstI, cnt, E, N);
    scan_block<<<nb, 256, 0, stream>>>(cnt, rowptr, bsums, dinv, N);
    scan_tops<<<1, 512, 0, stream>>>(bsums, boffs, nb);
    finalize_rowptr<<<nb, 256, 0, stream>>>(rowptr, boffs, N, E);
    scatter_kernel<<<1024, 256, 0, stream>>>(srcI, dstI, rowptr, cur, csr, E, N);

    wcvt2_kernel<<<(256 * 128 + 128 * 64 + 255) / 256, 256, 0, stream>>>(W1, W2, W1t, W2t);

    const int gblk = (N + 63) / 64;
    // layer 1
    gemm_mfma<256, 128, 2, true><<<gblk, 256, 0, stream>>>(x, W1t, dinv, bufA, N);
    spmm_relu128<<<(N + 3) / 4, 256, 0, stream>>>(bufA, rowptr, csr, dinv, b1, bufB, N);
    // layer 2
    gemm_mfma<128, 64, 1, false><<<gblk, 256, 0, stream>>>(bufB, W2t, dinv, bufA, N);
    spmm_relu64<<<(N + 3) / 4, 256, 0, stream>>>(bufA, rowptr, csr, dinv, b2, bufB, N);
    // head
    head_kernel<<<(N + 255) / 256, 256, 0, stream>>>(bufB, Wl, bl, out, N);
}

// Round 6
// 469.719 us; speedup vs baseline: 1.4184x; 1.0968x over previous
//
#include <hip/hip_runtime.h>

// ---------------------------------------------------------------------------
// GCN, bf16 data-path:
//  deg+pos (atomic returns slot, coalesced pos write) -> scan -> place (NO
//  atomic: csr[rowptr[d]+pos[e]]=src[e], fire-and-forget scattered stores) ->
//  GEMM1 (MFMA bf16) -> SpMM1 (16-deep pipelined gather) -> GEMM2 ->
//  SpMM2 -> head (thread-per-node).
// R5 lesson: atomic-with-return + dependent scattered write serialized the
// scatter (84us, 0.7% VALU, 17% HBM). Splitting claim (pass1) from placement
// (pass2) makes placement dependency-free.
// ---------------------------------------------------------------------------

typedef unsigned short ushort_t;
typedef unsigned int uint_t;
typedef __attribute__((ext_vector_type(8))) short short8;
typedef __attribute__((ext_vector_type(4))) float floatx4;

static __device__ __forceinline__ ushort_t f2bf(float f) {
    union { float f; uint_t u; } c; c.f = f;
    return (ushort_t)((c.u + 0x8000u) >> 16);
}
static __device__ __forceinline__ float bf2f(ushort_t h) {
    union { uint_t u; float f; } c; c.u = ((uint_t)h) << 16;
    return c.f;
}
static __device__ __forceinline__ float2 up2(uint_t p) {
    union { uint_t u; float f; } lo, hi;
    lo.u = p << 16; hi.u = p & 0xffff0000u;
    return make_float2(lo.f, hi.f);
}

// ------------------------------ CSR build ----------------------------------

// pass 1: degree count + per-edge slot (pos). 4 edges/thread, atomics in flight.
__global__ __launch_bounds__(256) void deg_pos_kernel(
    const int* __restrict__ dst, int* __restrict__ cnt, int* __restrict__ pos, int E) {
    int i4 = (blockIdx.x * 256 + threadIdx.x) * 4;
    if (i4 + 3 < E) {
        int4 d = *(const int4*)(dst + i4);
        int4 p;
        p.x = atomicAdd(&cnt[d.x], 1);
        p.y = atomicAdd(&cnt[d.y], 1);
        p.z = atomicAdd(&cnt[d.z], 1);
        p.w = atomicAdd(&cnt[d.w], 1);
        *(int4*)(pos + i4) = p;
    } else {
        for (int e = i4; e < E; e++)
            pos[e] = atomicAdd(&cnt[dst[e]], 1);
    }
}

// scan + dinv fused
__global__ void scan_block(const int* __restrict__ cnt, int* __restrict__ rowptr,
                           int* __restrict__ bsums, float* __restrict__ dinv, int n) {
    __shared__ int s[256];
    int i = blockIdx.x * 256 + threadIdx.x;
    int v = (i < n) ? cnt[i] : 0;
    if (i < n) dinv[i] = rsqrtf((float)(v + 1));   // +1 self loop
    s[threadIdx.x] = v;
    __syncthreads();
    for (int off = 1; off < 256; off <<= 1) {
        int t = (threadIdx.x >= off) ? s[threadIdx.x - off] : 0;
        __syncthreads();
        s[threadIdx.x] += t;
        __syncthreads();
    }
    if (i < n) rowptr[i] = s[threadIdx.x] - v;
    if (threadIdx.x == 255) bsums[blockIdx.x] = s[255];
}

__global__ void scan_tops(const int* __restrict__ bsums, int* __restrict__ boffs, int nb) {
    __shared__ int s[512];
    int v = (threadIdx.x < nb) ? bsums[threadIdx.x] : 0;
    s[threadIdx.x] = v;
    __syncthreads();
    for (int off = 1; off < 512; off <<= 1) {
        int t = (threadIdx.x >= off) ? s[threadIdx.x - off] : 0;
        __syncthreads();
        s[threadIdx.x] += t;
        __syncthreads();
    }
    if (threadIdx.x < nb) boffs[threadIdx.x] = s[threadIdx.x] - v;
}

__global__ void finalize_rowptr(int* __restrict__ rowptr, const int* __restrict__ boffs,
                                int n, int E) {
    int i = blockIdx.x * 256 + threadIdx.x;
    if (i < n) rowptr[i] += boffs[blockIdx.x];
    if (i == 0) rowptr[n] = E;
}

// pass 2: placement, no atomics — scattered stores fire-and-forget.
__global__ __launch_bounds__(256) void place_kernel(
    const int* __restrict__ src, const int* __restrict__ dst,
    const int* __restrict__ pos, const int* __restrict__ rowptr,
    int* __restrict__ csr, int E) {
    int i4 = (blockIdx.x * 256 + threadIdx.x) * 4;
    if (i4 + 3 < E) {
        int4 s = *(const int4*)(src + i4);
        int4 d = *(const int4*)(dst + i4);
        int4 p = *(const int4*)(pos + i4);
        csr[rowptr[d.x] + p.x] = s.x;
        csr[rowptr[d.y] + p.y] = s.y;
        csr[rowptr[d.z] + p.z] = s.z;
        csr[rowptr[d.w] + p.w] = s.w;
    } else {
        for (int e = i4; e < E; e++)
            csr[rowptr[dst[e]] + pos[e]] = src[e];
    }
}

// --------------- both weight transposes + bf16 convert, one launch ---------
__global__ void wcvt2_kernel(const float* __restrict__ W1, const float* __restrict__ W2,
                             ushort_t* __restrict__ W1t, ushort_t* __restrict__ W2t) {
    int i = blockIdx.x * 256 + threadIdx.x;
    if (i < 256 * 128) {
        int k = i / 128, n = i % 128;
        W1t[n * 256 + k] = f2bf(W1[i]);
    }
    int j = i - 256 * 128;
    if (j >= 0 && j < 128 * 64) {
        int k = j / 64, n = j % 64;
        W2t[n * 128 + k] = f2bf(W2[j]);
    }
}

// ------------------------------ MFMA GEMM ----------------------------------
// out[m][n] = bf16( dinv[m] * sum_k A[m][k]*Bt[n][k] )
template<int K, int NOUT, int NT, bool AFP32>
__global__ __launch_bounds__(256) void gemm_mfma(
    const void* __restrict__ Av, const ushort_t* __restrict__ Bt,
    const float* __restrict__ dinv, ushort_t* __restrict__ out, int M) {
    const int l = threadIdx.x & 63;
    const int wave = threadIdx.x >> 6;
    const int lrow = l & 15;
    const int lk8 = (l >> 4) * 8;
    const int m0 = blockIdx.x * 64;
    const int n0w = wave * (NT * 16);

    floatx4 acc[4][NT];
    #pragma unroll
    for (int mt = 0; mt < 4; mt++)
        #pragma unroll
        for (int nt = 0; nt < NT; nt++)
            acc[mt][nt] = (floatx4){0.f, 0.f, 0.f, 0.f};

    const float*    Af = (const float*)Av;
    const ushort_t* Ab = (const ushort_t*)Av;

    int rows[4];
    #pragma unroll
    for (int mt = 0; mt < 4; mt++) {
        int r = m0 + mt * 16 + lrow;
        rows[mt] = (r < M) ? r : (M - 1);
    }

    for (int k0 = 0; k0 < K; k0 += 32) {
        short8 afr[4];
        #pragma unroll
        for (int mt = 0; mt < 4; mt++) {
            if (AFP32) {
                const float* ap = Af + (size_t)rows[mt] * K + k0 + lk8;
                float4 u = *(const float4*)ap;
                float4 v = *(const float4*)(ap + 4);
                short8 t;
                t[0] = (short)f2bf(u.x); t[1] = (short)f2bf(u.y);
                t[2] = (short)f2bf(u.z); t[3] = (short)f2bf(u.w);
                t[4] = (short)f2bf(v.x); t[5] = (short)f2bf(v.y);
                t[6] = (short)f2bf(v.z); t[7] = (short)f2bf(v.w);
                afr[mt] = t;
            } else {
                afr[mt] = *(const short8*)(Ab + (size_t)rows[mt] * K + k0 + lk8);
            }
        }
        short8 bfr[NT];
        #pragma unroll
        for (int nt = 0; nt < NT; nt++) {
            int n = n0w + nt * 16 + lrow;
            bfr[nt] = *(const short8*)(Bt + (size_t)n * K + k0 + lk8);
        }
        #pragma unroll
        for (int mt = 0; mt < 4; mt++)
            #pragma unroll
            for (int nt = 0; nt < NT; nt++)
                acc[mt][nt] = __builtin_amdgcn_mfma_f32_16x16x32_bf16(
                    afr[mt], bfr[nt], acc[mt][nt], 0, 0, 0);
    }

    const int r0 = (l >> 4) * 4;
    #pragma unroll
    for (int mt = 0; mt < 4; mt++) {
        int mbase = m0 + mt * 16 + r0;
        float4 dv = *(const float4*)&dinv[mbase];   // dinv padded past N
        float d[4] = {dv.x, dv.y, dv.z, dv.w};
        #pragma unroll
        for (int i = 0; i < 4; i++) {
            int m = mbase + i;
            if (m < M) {
                #pragma unroll
                for (int nt = 0; nt < NT; nt++)
                    out[(size_t)m * NOUT + n0w + nt * 16 + lrow] =
                        f2bf(acc[mt][nt][i] * d[i]);
            }
        }
    }
}

// ------------------------------ SpMM 1 -------------------------------------
// F=128, bf16 in/out. Wave per node; coalesced index load + shfl broadcast;
// up to 16 gathers in flight.
__global__ __launch_bounds__(256) void spmm_relu128(
    const ushort_t* __restrict__ Mm, const int* __restrict__ rowptr,
    const int* __restrict__ csr, const float* __restrict__ dinv,
    const float* __restrict__ bias, ushort_t* __restrict__ out, int n) {
    int v = (blockIdx.x * 256 + threadIdx.x) >> 6;
    int lane = threadIdx.x & 63;
    if (v >= n) return;
    int jb = rowptr[v], je = rowptr[v + 1];
    int cntn = je - jb;

    float2 accA = up2(*(const uint_t*)(Mm + (size_t)v * 128 + lane * 2));  // self
    float2 accB = make_float2(0.f, 0.f);

    for (int base = 0; base < cntn; base += 64) {
        int m = cntn - base; if (m > 64) m = 64;
        int idx = (base + lane < cntn) ? csr[jb + base + lane] : 0;
        int jj = 0;
        for (; jj + 16 <= m; jj += 16) {
            int sI[16];
            #pragma unroll
            for (int t = 0; t < 16; t++) sI[t] = __shfl(idx, jj + t);
            uint_t p[16];
            #pragma unroll
            for (int t = 0; t < 16; t++)
                p[t] = *(const uint_t*)(Mm + (size_t)sI[t] * 128 + lane * 2);
            #pragma unroll
            for (int t = 0; t < 16; t++) {
                float2 f = up2(p[t]);
                if (t & 1) { accB.x += f.x; accB.y += f.y; }
                else       { accA.x += f.x; accA.y += f.y; }
            }
        }
        for (; jj + 8 <= m; jj += 8) {
            int sI[8];
            #pragma unroll
            for (int t = 0; t < 8; t++) sI[t] = __shfl(idx, jj + t);
            uint_t p[8];
            #pragma unroll
            for (int t = 0; t < 8; t++)
                p[t] = *(const uint_t*)(Mm + (size_t)sI[t] * 128 + lane * 2);
            #pragma unroll
            for (int t = 0; t < 8; t++) {
                float2 f = up2(p[t]);
                if (t & 1) { accB.x += f.x; accB.y += f.y; }
                else       { accA.x += f.x; accA.y += f.y; }
            }
        }
        for (; jj < m; jj++) {
            int s = __shfl(idx, jj);
            float2 f = up2(*(const uint_t*)(Mm + (size_t)s * 128 + lane * 2));
            accA.x += f.x; accA.y += f.y;
        }
    }
    float d = dinv[v];
    float2 bv = *(const float2*)&bias[lane * 2];
    float rx = fmaxf(d * (accA.x + accB.x) + bv.x, 0.f);
    float ry = fmaxf(d * (accA.y + accB.y) + bv.y, 0.f);
    uint_t packed = ((uint_t)f2bf(ry) << 16) | (uint_t)f2bf(rx);
    *(uint_t*)(out + (size_t)v * 128 + lane * 2) = packed;
}

// ------------------------------ SpMM 2 -------------------------------------
// F=64, bf16 in, bf16 out. Wave per node; up to 16 gathers in flight.
__global__ __launch_bounds__(256) void spmm_relu64(
    const ushort_t* __restrict__ Mm, const int* __restrict__ rowptr,
    const int* __restrict__ csr, const float* __restrict__ dinv,
    const float* __restrict__ bias, ushort_t* __restrict__ out, int n) {
    int v = (blockIdx.x * 256 + threadIdx.x) >> 6;
    int lane = threadIdx.x & 63;
    if (v >= n) return;
    int jb = rowptr[v], je = rowptr[v + 1];
    int cntn = je - jb;

    float accA = bf2f(Mm[(size_t)v * 64 + lane]);   // self
    float accB = 0.f;

    for (int base = 0; base < cntn; base += 64) {
        int m = cntn - base; if (m > 64) m = 64;
        int idx = (base + lane < cntn) ? csr[jb + base + lane] : 0;
        int jj = 0;
        for (; jj + 16 <= m; jj += 16) {
            int sI[16];
            #pragma unroll
            for (int t = 0; t < 16; t++) sI[t] = __shfl(idx, jj + t);
            ushort_t p[16];
            #pragma unroll
            for (int t = 0; t < 16; t++)
                p[t] = Mm[(size_t)sI[t] * 64 + lane];
            #pragma unroll
            for (int t = 0; t < 16; t++) {
                if (t & 1) accB += bf2f(p[t]);
                else       accA += bf2f(p[t]);
            }
        }
        for (; jj + 8 <= m; jj += 8) {
            int sI[8];
            #pragma unroll
            for (int t = 0; t < 8; t++) sI[t] = __shfl(idx, jj + t);
            ushort_t p[8];
            #pragma unroll
            for (int t = 0; t < 8; t++)
                p[t] = Mm[(size_t)sI[t] * 64 + lane];
            #pragma unroll
            for (int t = 0; t < 8; t++) {
                if (t & 1) accB += bf2f(p[t]);
                else       accA += bf2f(p[t]);
            }
        }
        for (; jj < m; jj++) {
            int s = __shfl(idx, jj);
            accA += bf2f(Mm[(size_t)s * 64 + lane]);
        }
    }
    float r = fmaxf(dinv[v] * (accA + accB) + bias[lane], 0.f);
    out[(size_t)v * 64 + lane] = f2bf(r);
}

// ------------------------------ head ---------------------------------------
__global__ __launch_bounds__(256) void head_kernel(
    const ushort_t* __restrict__ h2, const float* __restrict__ Wl,
    const float* __restrict__ bl, float* __restrict__ out, int n) {
    __shared__ float Ws[64 * 10];
    __shared__ float bs[10];
    for (int i = threadIdx.x; i < 640; i += 256) Ws[i] = Wl[i];
    if (threadIdx.x < 10) bs[threadIdx.x] = bl[threadIdx.x];
    __syncthreads();
    int v = blockIdx.x * 256 + threadIdx.x;
    if (v >= n) return;
    float acc[10];
    #pragma unroll
    for (int c = 0; c < 10; c++) acc[c] = bs[c];
    const ushort_t* hrow = &h2[(size_t)v * 64];
    #pragma unroll
    for (int k0 = 0; k0 < 64; k0 += 8) {
        short8 hv = *(const short8*)&hrow[k0];
        #pragma unroll
        for (int kk = 0; kk < 8; kk++) {
            float hf = bf2f((ushort_t)hv[kk]);
            #pragma unroll
            for (int c = 0; c < 10; c++)
                acc[c] += hf * Ws[(k0 + kk) * 10 + c];
        }
    }
    float m = acc[0];
    #pragma unroll
    for (int c = 1; c < 10; c++) m = fmaxf(m, acc[c]);
    float s = 0.f;
    #pragma unroll
    for (int c = 0; c < 10; c++) s += expf(acc[c] - m);
    float lse = logf(s);
    #pragma unroll
    for (int c = 0; c < 10; c++) out[(size_t)v * 10 + c] = acc[c] - m - lse;
}

// ------------------------------ launch -------------------------------------
extern "C" void kernel_launch(void* const* d_in, const int* in_sizes, int n_in,
                              void* d_out, int out_size, void* d_ws, size_t ws_size,
                              hipStream_t stream) {
    const float* x   = (const float*)d_in[0];
    const int*   ei  = (const int*)d_in[1];      // int32 (JAX x64 disabled)
    const float* W1  = (const float*)d_in[2];
    const float* b1  = (const float*)d_in[3];
    const float* W2  = (const float*)d_in[4];
    const float* b2  = (const float*)d_in[5];
    const float* Wl  = (const float*)d_in[6];
    const float* bl  = (const float*)d_in[7];
    float*       out = (float*)d_out;

    const int N = in_sizes[0] / 256;   // 100000
    const int E = in_sizes[1] / 2;     // 1600000
    const int* srcI = ei;
    const int* dstI = ei + E;

    char* ws = (char*)d_ws;
    size_t off = 0;
    auto alloc = [&](size_t bytes) -> void* {
        void* p = ws + off;
        off = (off + bytes + 255) & ~(size_t)255;
        return p;
    };
    int*      cnt    = (int*)alloc((size_t)N * 4);
    int*      rowptr = (int*)alloc((size_t)(N + 1) * 4);
    float*    dinv   = (float*)alloc((size_t)(N + 64) * 4);   // padded for float4 reads
    int*      csr    = (int*)alloc((size_t)E * 4);
    int*      pos    = (int*)alloc((size_t)E * 4);
    int*      bsums  = (int*)alloc(512 * 4);
    int*      boffs  = (int*)alloc(512 * 4);
    ushort_t* W1t    = (ushort_t*)alloc((size_t)128 * 256 * 2);
    ushort_t* W2t    = (ushort_t*)alloc((size_t)64 * 128 * 2);
    ushort_t* bufA   = (ushort_t*)alloc((size_t)N * 128 * 2); // M1' / M2' (bf16)
    ushort_t* bufB   = (ushort_t*)alloc((size_t)N * 128 * 2); // h1 / h2 (bf16)

    hipMemsetAsync(cnt, 0, (size_t)N * 4, stream);

    const int nb = (N + 255) / 256;  // 391 <= 512
    const int eb4 = (E + 1023) / 1024;  // blocks covering 4 edges/thread
    deg_pos_kernel<<<eb4, 256, 0, stream>>>(dstI, cnt, pos, E);
    scan_block<<<nb, 256, 0, stream>>>(cnt, rowptr, bsums, dinv, N);
    scan_tops<<<1, 512, 0, stream>>>(bsums, boffs, nb);
    finalize_rowptr<<<nb, 256, 0, stream>>>(rowptr, boffs, N, E);
    place_kernel<<<eb4, 256, 0, stream>>>(srcI, dstI, pos, rowptr, csr, E);

    wcvt2_kernel<<<(256 * 128 + 128 * 64 + 255) / 256, 256, 0, stream>>>(W1, W2, W1t, W2t);

    const int gblk = (N + 63) / 64;
    // layer 1
    gemm_mfma<256, 128, 2, true><<<gblk, 256, 0, stream>>>(x, W1t, dinv, bufA, N);
    spmm_relu128<<<(N + 3) / 4, 256, 0, stream>>>(bufA, rowptr, csr, dinv, b1, bufB, N);
    // layer 2
    gemm_mfma<128, 64, 1, false><<<gblk, 256, 0, stream>>>(bufB, W2t, dinv, bufA, N);
    spmm_relu64<<<(N + 3) / 4, 256, 0, stream>>>(bufA, rowptr, csr, dinv, b2, bufB, N);
    // head
    head_kernel<<<(N + 255) / 256, 256, 0, stream>>>(bufB, Wl, bl, out, N);
}

// Round 7
// 469.692 us; speedup vs baseline: 1.4185x; 1.0001x over previous
//
#include <hip/hip_runtime.h>

// ---------------------------------------------------------------------------
// GCN, bf16 data-path:
//  deg+pos -> scan -> place -> GEMM1 (MFMA, reg-pipelined) -> SpMM1 ->
//  GEMM2 -> SpMM2 -> head.
// R6 lesson: GEMM was MLP-starved (3% mfma, 8% valu, 12% hbm): 10 loads +
// vmcnt(0) per K-iter. Fix: preload ALL B fragments to regs (L2-hot) and
// 3-stage software-prefetch A, ~24 loads in flight per wave.
// ---------------------------------------------------------------------------

typedef unsigned short ushort_t;
typedef unsigned int uint_t;
typedef __attribute__((ext_vector_type(8))) short short8;
typedef __attribute__((ext_vector_type(4))) float floatx4;

static __device__ __forceinline__ ushort_t f2bf(float f) {
    union { float f; uint_t u; } c; c.f = f;
    return (ushort_t)((c.u + 0x8000u) >> 16);
}
static __device__ __forceinline__ float bf2f(ushort_t h) {
    union { uint_t u; float f; } c; c.u = ((uint_t)h) << 16;
    return c.f;
}
static __device__ __forceinline__ float2 up2(uint_t p) {
    union { uint_t u; float f; } lo, hi;
    lo.u = p << 16; hi.u = p & 0xffff0000u;
    return make_float2(lo.f, hi.f);
}

// ------------------------------ CSR build ----------------------------------

__global__ __launch_bounds__(256) void deg_pos_kernel(
    const int* __restrict__ dst, int* __restrict__ cnt, int* __restrict__ pos, int E) {
    int i4 = (blockIdx.x * 256 + threadIdx.x) * 4;
    if (i4 + 3 < E) {
        int4 d = *(const int4*)(dst + i4);
        int4 p;
        p.x = atomicAdd(&cnt[d.x], 1);
        p.y = atomicAdd(&cnt[d.y], 1);
        p.z = atomicAdd(&cnt[d.z], 1);
        p.w = atomicAdd(&cnt[d.w], 1);
        *(int4*)(pos + i4) = p;
    } else {
        for (int e = i4; e < E; e++)
            pos[e] = atomicAdd(&cnt[dst[e]], 1);
    }
}

__global__ void scan_block(const int* __restrict__ cnt, int* __restrict__ rowptr,
                           int* __restrict__ bsums, float* __restrict__ dinv, int n) {
    __shared__ int s[256];
    int i = blockIdx.x * 256 + threadIdx.x;
    int v = (i < n) ? cnt[i] : 0;
    if (i < n) dinv[i] = rsqrtf((float)(v + 1));   // +1 self loop
    s[threadIdx.x] = v;
    __syncthreads();
    for (int off = 1; off < 256; off <<= 1) {
        int t = (threadIdx.x >= off) ? s[threadIdx.x - off] : 0;
        __syncthreads();
        s[threadIdx.x] += t;
        __syncthreads();
    }
    if (i < n) rowptr[i] = s[threadIdx.x] - v;
    if (threadIdx.x == 255) bsums[blockIdx.x] = s[255];
}

__global__ void scan_tops(const int* __restrict__ bsums, int* __restrict__ boffs, int nb) {
    __shared__ int s[512];
    int v = (threadIdx.x < nb) ? bsums[threadIdx.x] : 0;
    s[threadIdx.x] = v;
    __syncthreads();
    for (int off = 1; off < 512; off <<= 1) {
        int t = (threadIdx.x >= off) ? s[threadIdx.x - off] : 0;
        __syncthreads();
        s[threadIdx.x] += t;
        __syncthreads();
    }
    if (threadIdx.x < nb) boffs[threadIdx.x] = s[threadIdx.x] - v;
}

__global__ void finalize_rowptr(int* __restrict__ rowptr, const int* __restrict__ boffs,
                                int n, int E) {
    int i = blockIdx.x * 256 + threadIdx.x;
    if (i < n) rowptr[i] += boffs[blockIdx.x];
    if (i == 0) rowptr[n] = E;
}

__global__ __launch_bounds__(256) void place_kernel(
    const int* __restrict__ src, const int* __restrict__ dst,
    const int* __restrict__ pos, const int* __restrict__ rowptr,
    int* __restrict__ csr, int E) {
    int i4 = (blockIdx.x * 256 + threadIdx.x) * 4;
    if (i4 + 3 < E) {
        int4 s = *(const int4*)(src + i4);
        int4 d = *(const int4*)(dst + i4);
        int4 p = *(const int4*)(pos + i4);
        csr[rowptr[d.x] + p.x] = s.x;
        csr[rowptr[d.y] + p.y] = s.y;
        csr[rowptr[d.z] + p.z] = s.z;
        csr[rowptr[d.w] + p.w] = s.w;
    } else {
        for (int e = i4; e < E; e++)
            csr[rowptr[dst[e]] + pos[e]] = src[e];
    }
}

// --------------- both weight transposes + bf16 convert, one launch ---------
__global__ void wcvt2_kernel(const float* __restrict__ W1, const float* __restrict__ W2,
                             ushort_t* __restrict__ W1t, ushort_t* __restrict__ W2t) {
    int i = blockIdx.x * 256 + threadIdx.x;
    if (i < 256 * 128) {
        int k = i / 128, n = i % 128;
        W1t[n * 256 + k] = f2bf(W1[i]);
    }
    int j = i - 256 * 128;
    if (j >= 0 && j < 128 * 64) {
        int k = j / 64, n = j % 64;
        W2t[n * 128 + k] = f2bf(W2[j]);
    }
}

// ------------------------------ MFMA GEMM ----------------------------------
// out[m][n] = bf16( dinv[m] * sum_k A[m][k]*Bt[n][k] )
// All B fragments preloaded to registers; A software-prefetched 3 deep.
template<int K, int NOUT, int NT, bool AFP32>
__global__ __launch_bounds__(256) void gemm_mfma(
    const void* __restrict__ Av, const ushort_t* __restrict__ Bt,
    const float* __restrict__ dinv, ushort_t* __restrict__ out, int M) {
    const int l = threadIdx.x & 63;
    const int wave = threadIdx.x >> 6;
    const int lrow = l & 15;
    const int lk8 = (l >> 4) * 8;
    const int m0 = blockIdx.x * 64;
    const int n0w = wave * (NT * 16);
    constexpr int KI = K / 32;
    constexpr int NS = 3;              // A prefetch stages

    const float*    Af = (const float*)Av;
    const ushort_t* Ab = (const ushort_t*)Av;

    int rows[4];
    #pragma unroll
    for (int mt = 0; mt < 4; mt++) {
        int r = m0 + mt * 16 + lrow;
        rows[mt] = (r < M) ? r : (M - 1);
    }

    // ---- preload ALL B fragments (Bt is tiny + L2-hot; shared by all blocks)
    short8 bfr[KI][NT];
    #pragma unroll
    for (int kk = 0; kk < KI; kk++)
        #pragma unroll
        for (int nt = 0; nt < NT; nt++)
            bfr[kk][nt] = *(const short8*)(
                Bt + (size_t)(n0w + nt * 16 + lrow) * K + kk * 32 + lk8);

    // ---- A staging buffers
    float4 au[NS][4], av[NS][4];   // fp32 path
    short8 ab[NS][4];              // bf16 path

    auto loadA = [&](int st, int kk) {
        #pragma unroll
        for (int mt = 0; mt < 4; mt++) {
            if (AFP32) {
                const float* ap = Af + (size_t)rows[mt] * K + kk * 32 + lk8;
                au[st][mt] = *(const float4*)ap;
                av[st][mt] = *(const float4*)(ap + 4);
            } else {
                ab[st][mt] = *(const short8*)(Ab + (size_t)rows[mt] * K + kk * 32 + lk8);
            }
        }
    };

    loadA(0, 0);
    if (KI > 1) loadA(1, 1);
    if (KI > 2) loadA(2, 2);

    floatx4 acc[4][NT];
    #pragma unroll
    for (int mt = 0; mt < 4; mt++)
        #pragma unroll
        for (int nt = 0; nt < NT; nt++)
            acc[mt][nt] = (floatx4){0.f, 0.f, 0.f, 0.f};

    #pragma unroll
    for (int kk = 0; kk < KI; kk++) {
        const int st = kk % NS;
        short8 afr[4];
        #pragma unroll
        for (int mt = 0; mt < 4; mt++) {
            if (AFP32) {
                float4 u = au[st][mt], v = av[st][mt];
                short8 t;
                t[0] = (short)f2bf(u.x); t[1] = (short)f2bf(u.y);
                t[2] = (short)f2bf(u.z); t[3] = (short)f2bf(u.w);
                t[4] = (short)f2bf(v.x); t[5] = (short)f2bf(v.y);
                t[6] = (short)f2bf(v.z); t[7] = (short)f2bf(v.w);
                afr[mt] = t;
            } else {
                afr[mt] = ab[st][mt];
            }
        }
        if (kk + NS < KI) loadA(st, kk + NS);   // refill consumed stage
        #pragma unroll
        for (int mt = 0; mt < 4; mt++)
            #pragma unroll
            for (int nt = 0; nt < NT; nt++)
                acc[mt][nt] = __builtin_amdgcn_mfma_f32_16x16x32_bf16(
                    afr[mt], bfr[kk][nt], acc[mt][nt], 0, 0, 0);
    }

    const int r0 = (l >> 4) * 4;
    #pragma unroll
    for (int mt = 0; mt < 4; mt++) {
        int mbase = m0 + mt * 16 + r0;
        float4 dv = *(const float4*)&dinv[mbase];   // dinv padded past N
        float d[4] = {dv.x, dv.y, dv.z, dv.w};
        #pragma unroll
        for (int i = 0; i < 4; i++) {
            int m = mbase + i;
            if (m < M) {
                #pragma unroll
                for (int nt = 0; nt < NT; nt++)
                    out[(size_t)m * NOUT + n0w + nt * 16 + lrow] =
                        f2bf(acc[mt][nt][i] * d[i]);
            }
        }
    }
}

// ------------------------------ SpMM 1 -------------------------------------
__global__ __launch_bounds__(256) void spmm_relu128(
    const ushort_t* __restrict__ Mm, const int* __restrict__ rowptr,
    const int* __restrict__ csr, const float* __restrict__ dinv,
    const float* __restrict__ bias, ushort_t* __restrict__ out, int n) {
    int v = (blockIdx.x * 256 + threadIdx.x) >> 6;
    int lane = threadIdx.x & 63;
    if (v >= n) return;
    int jb = rowptr[v], je = rowptr[v + 1];
    int cntn = je - jb;

    float2 accA = up2(*(const uint_t*)(Mm + (size_t)v * 128 + lane * 2));  // self
    float2 accB = make_float2(0.f, 0.f);

    for (int base = 0; base < cntn; base += 64) {
        int m = cntn - base; if (m > 64) m = 64;
        int idx = (base + lane < cntn) ? csr[jb + base + lane] : 0;
        int jj = 0;
        for (; jj + 16 <= m; jj += 16) {
            int sI[16];
            #pragma unroll
            for (int t = 0; t < 16; t++) sI[t] = __shfl(idx, jj + t);
            uint_t p[16];
            #pragma unroll
            for (int t = 0; t < 16; t++)
                p[t] = *(const uint_t*)(Mm + (size_t)sI[t] * 128 + lane * 2);
            #pragma unroll
            for (int t = 0; t < 16; t++) {
                float2 f = up2(p[t]);
                if (t & 1) { accB.x += f.x; accB.y += f.y; }
                else       { accA.x += f.x; accA.y += f.y; }
            }
        }
        for (; jj + 8 <= m; jj += 8) {
            int sI[8];
            #pragma unroll
            for (int t = 0; t < 8; t++) sI[t] = __shfl(idx, jj + t);
            uint_t p[8];
            #pragma unroll
            for (int t = 0; t < 8; t++)
                p[t] = *(const uint_t*)(Mm + (size_t)sI[t] * 128 + lane * 2);
            #pragma unroll
            for (int t = 0; t < 8; t++) {
                float2 f = up2(p[t]);
                if (t & 1) { accB.x += f.x; accB.y += f.y; }
                else       { accA.x += f.x; accA.y += f.y; }
            }
        }
        for (; jj < m; jj++) {
            int s = __shfl(idx, jj);
            float2 f = up2(*(const uint_t*)(Mm + (size_t)s * 128 + lane * 2));
            accA.x += f.x; accA.y += f.y;
        }
    }
    float d = dinv[v];
    float2 bv = *(const float2*)&bias[lane * 2];
    float rx = fmaxf(d * (accA.x + accB.x) + bv.x, 0.f);
    float ry = fmaxf(d * (accA.y + accB.y) + bv.y, 0.f);
    uint_t packed = ((uint_t)f2bf(ry) << 16) | (uint_t)f2bf(rx);
    *(uint_t*)(out + (size_t)v * 128 + lane * 2) = packed;
}

// ------------------------------ SpMM 2 -------------------------------------
__global__ __launch_bounds__(256) void spmm_relu64(
    const ushort_t* __restrict__ Mm, const int* __restrict__ rowptr,
    const int* __restrict__ csr, const float* __restrict__ dinv,
    const float* __restrict__ bias, ushort_t* __restrict__ out, int n) {
    int v = (blockIdx.x * 256 + threadIdx.x) >> 6;
    int lane = threadIdx.x & 63;
    if (v >= n) return;
    int jb = rowptr[v], je = rowptr[v + 1];
    int cntn = je - jb;

    float accA = bf2f(Mm[(size_t)v * 64 + lane]);   // self
    float accB = 0.f;

    for (int base = 0; base < cntn; base += 64) {
        int m = cntn - base; if (m > 64) m = 64;
        int idx = (base + lane < cntn) ? csr[jb + base + lane] : 0;
        int jj = 0;
        for (; jj + 16 <= m; jj += 16) {
            int sI[16];
            #pragma unroll
            for (int t = 0; t < 16; t++) sI[t] = __shfl(idx, jj + t);
            ushort_t p[16];
            #pragma unroll
            for (int t = 0; t < 16; t++)
                p[t] = Mm[(size_t)sI[t] * 64 + lane];
            #pragma unroll
            for (int t = 0; t < 16; t++) {
                if (t & 1) accB += bf2f(p[t]);
                else       accA += bf2f(p[t]);
            }
        }
        for (; jj + 8 <= m; jj += 8) {
            int sI[8];
            #pragma unroll
            for (int t = 0; t < 8; t++) sI[t] = __shfl(idx, jj + t);
            ushort_t p[8];
            #pragma unroll
            for (int t = 0; t < 8; t++)
                p[t] = Mm[(size_t)sI[t] * 64 + lane];
            #pragma unroll
            for (int t = 0; t < 8; t++) {
                if (t & 1) accB += bf2f(p[t]);
                else       accA += bf2f(p[t]);
            }
        }
        for (; jj < m; jj++) {
            int s = __shfl(idx, jj);
            accA += bf2f(Mm[(size_t)s * 64 + lane]);
        }
    }
    float r = fmaxf(dinv[v] * (accA + accB) + bias[lane], 0.f);
    out[(size_t)v * 64 + lane] = f2bf(r);
}

// ------------------------------ head ---------------------------------------
__global__ __launch_bounds__(256) void head_kernel(
    const ushort_t* __restrict__ h2, const float* __restrict__ Wl,
    const float* __restrict__ bl, float* __restrict__ out, int n) {
    __shared__ float Ws[64 * 10];
    __shared__ float bs[10];
    for (int i = threadIdx.x; i < 640; i += 256) Ws[i] = Wl[i];
    if (threadIdx.x < 10) bs[threadIdx.x] = bl[threadIdx.x];
    __syncthreads();
    int v = blockIdx.x * 256 + threadIdx.x;
    if (v >= n) return;
    float acc[10];
    #pragma unroll
    for (int c = 0; c < 10; c++) acc[c] = bs[c];
    const ushort_t* hrow = &h2[(size_t)v * 64];
    #pragma unroll
    for (int k0 = 0; k0 < 64; k0 += 8) {
        short8 hv = *(const short8*)&hrow[k0];
        #pragma unroll
        for (int kk = 0; kk < 8; kk++) {
            float hf = bf2f((ushort_t)hv[kk]);
            #pragma unroll
            for (int c = 0; c < 10; c++)
                acc[c] += hf * Ws[(k0 + kk) * 10 + c];
        }
    }
    float m = acc[0];
    #pragma unroll
    for (int c = 1; c < 10; c++) m = fmaxf(m, acc[c]);
    float s = 0.f;
    #pragma unroll
    for (int c = 0; c < 10; c++) s += expf(acc[c] - m);
    float lse = logf(s);
    #pragma unroll
    for (int c = 0; c < 10; c++) out[(size_t)v * 10 + c] = acc[c] - m - lse;
}

// ------------------------------ launch -------------------------------------
extern "C" void kernel_launch(void* const* d_in, const int* in_sizes, int n_in,
                              void* d_out, int out_size, void* d_ws, size_t ws_size,
                              hipStream_t stream) {
    const float* x   = (const float*)d_in[0];
    const int*   ei  = (const int*)d_in[1];      // int32 (JAX x64 disabled)
    const float* W1  = (const float*)d_in[2];
    const float* b1  = (const float*)d_in[3];
    const float* W2  = (const float*)d_in[4];
    const float* b2  = (const float*)d_in[5];
    const float* Wl  = (const float*)d_in[6];
    const float* bl  = (const float*)d_in[7];
    float*       out = (float*)d_out;

    const int N = in_sizes[0] / 256;   // 100000
    const int E = in_sizes[1] / 2;     // 1600000
    const int* srcI = ei;
    const int* dstI = ei + E;

    char* ws = (char*)d_ws;
    size_t off = 0;
    auto alloc = [&](size_t bytes) -> void* {
        void* p = ws + off;
        off = (off + bytes + 255) & ~(size_t)255;
        return p;
    };
    int*      cnt    = (int*)alloc((size_t)N * 4);
    int*      rowptr = (int*)alloc((size_t)(N + 1) * 4);
    float*    dinv   = (float*)alloc((size_t)(N + 64) * 4);   // padded for float4 reads
    int*      csr    = (int*)alloc((size_t)E * 4);
    int*      pos    = (int*)alloc((size_t)E * 4);
    int*      bsums  = (int*)alloc(512 * 4);
    int*      boffs  = (int*)alloc(512 * 4);
    ushort_t* W1t    = (ushort_t*)alloc((size_t)128 * 256 * 2);
    ushort_t* W2t    = (ushort_t*)alloc((size_t)64 * 128 * 2);
    ushort_t* bufA   = (ushort_t*)alloc((size_t)N * 128 * 2); // M1' / M2' (bf16)
    ushort_t* bufB   = (ushort_t*)alloc((size_t)N * 128 * 2); // h1 / h2 (bf16)

    hipMemsetAsync(cnt, 0, (size_t)N * 4, stream);

    const int nb = (N + 255) / 256;  // 391 <= 512
    const int eb4 = (E + 1023) / 1024;
    deg_pos_kernel<<<eb4, 256, 0, stream>>>(dstI, cnt, pos, E);
    scan_block<<<nb, 256, 0, stream>>>(cnt, rowptr, bsums, dinv, N);
    scan_tops<<<1, 512, 0, stream>>>(bsums, boffs, nb);
    finalize_rowptr<<<nb, 256, 0, stream>>>(rowptr, boffs, N, E);
    place_kernel<<<eb4, 256, 0, stream>>>(srcI, dstI, pos, rowptr, csr, E);

    wcvt2_kernel<<<(256 * 128 + 128 * 64 + 255) / 256, 256, 0, stream>>>(W1, W2, W1t, W2t);

    const int gblk = (N + 63) / 64;
    // layer 1
    gemm_mfma<256, 128, 2, true><<<gblk, 256, 0, stream>>>(x, W1t, dinv, bufA, N);
    spmm_relu128<<<(N + 3) / 4, 256, 0, stream>>>(bufA, rowptr, csr, dinv, b1, bufB, N);
    // layer 2
    gemm_mfma<128, 64, 1, false><<<gblk, 256, 0, stream>>>(bufB, W2t, dinv, bufA, N);
    spmm_relu64<<<(N + 3) / 4, 256, 0, stream>>>(bufA, rowptr, csr, dinv, b2, bufB, N);
    // head
    head_kernel<<<(N + 255) / 256, 256, 0, stream>>>(bufB, Wl, bl, out, N);
}

// Round 8
// 436.776 us; speedup vs baseline: 1.5254x; 1.0754x over previous
//
#include <hip/hip_runtime.h>

// ---------------------------------------------------------------------------
// GCN, bf16 data-path:
//  deg+pos -> scan -> place -> GEMM1 (m97-style global_load_lds dbuf MFMA) ->
//  SpMM1 -> GEMM2 (same) -> SpMM2 -> head.
// R7 lesson: register-level software pipelining is re-sunk by the compiler
// (VGPR stayed 68). global_load_lds is side-effecting => cannot be sunk past
// barriers; LDS dbuf gives the MLP the scheduler refused. XOR-chunk swizzle
// (in the GLOBAL source address, LDS dst stays lane-contiguous) keeps
// ds_reads at <=2-way bank conflicts (free per m136).
// ---------------------------------------------------------------------------

typedef unsigned short ushort_t;
typedef unsigned int uint_t;
typedef __attribute__((ext_vector_type(8))) short short8;
typedef __attribute__((ext_vector_type(4))) float floatx4;

static __device__ __forceinline__ ushort_t f2bf(float f) {
    union { float f; uint_t u; } c; c.f = f;
    return (ushort_t)((c.u + 0x8000u) >> 16);
}
static __device__ __forceinline__ float bf2f(ushort_t h) {
    union { uint_t u; float f; } c; c.u = ((uint_t)h) << 16;
    return c.f;
}
static __device__ __forceinline__ float2 up2(uint_t p) {
    union { uint_t u; float f; } lo, hi;
    lo.u = p << 16; hi.u = p & 0xffff0000u;
    return make_float2(lo.f, hi.f);
}
// async global->LDS, 16B per lane; LDS dst = wave-uniform base + lane*16.
static __device__ __forceinline__ void ld_lds16(void* lds, const void* g) {
    __builtin_amdgcn_global_load_lds(
        (const __attribute__((address_space(1))) unsigned int*)g,
        (__attribute__((address_space(3))) unsigned int*)lds, 16, 0, 0);
}

// ------------------------------ CSR build ----------------------------------

__global__ __launch_bounds__(256) void deg_pos_kernel(
    const int* __restrict__ dst, int* __restrict__ cnt, int* __restrict__ pos, int E) {
    int i4 = (blockIdx.x * 256 + threadIdx.x) * 4;
    if (i4 + 3 < E) {
        int4 d = *(const int4*)(dst + i4);
        int4 p;
        p.x = atomicAdd(&cnt[d.x], 1);
        p.y = atomicAdd(&cnt[d.y], 1);
        p.z = atomicAdd(&cnt[d.z], 1);
        p.w = atomicAdd(&cnt[d.w], 1);
        *(int4*)(pos + i4) = p;
    } else {
        for (int e = i4; e < E; e++)
            pos[e] = atomicAdd(&cnt[dst[e]], 1);
    }
}

__global__ void scan_block(const int* __restrict__ cnt, int* __restrict__ rowptr,
                           int* __restrict__ bsums, float* __restrict__ dinv, int n) {
    __shared__ int s[256];
    int i = blockIdx.x * 256 + threadIdx.x;
    int v = (i < n) ? cnt[i] : 0;
    if (i < n) dinv[i] = rsqrtf((float)(v + 1));   // +1 self loop
    s[threadIdx.x] = v;
    __syncthreads();
    for (int off = 1; off < 256; off <<= 1) {
        int t = (threadIdx.x >= off) ? s[threadIdx.x - off] : 0;
        __syncthreads();
        s[threadIdx.x] += t;
        __syncthreads();
    }
    if (i < n) rowptr[i] = s[threadIdx.x] - v;
    if (threadIdx.x == 255) bsums[blockIdx.x] = s[255];
}

__global__ void scan_tops(const int* __restrict__ bsums, int* __restrict__ boffs, int nb) {
    __shared__ int s[512];
    int v = (threadIdx.x < nb) ? bsums[threadIdx.x] : 0;
    s[threadIdx.x] = v;
    __syncthreads();
    for (int off = 1; off < 512; off <<= 1) {
        int t = (threadIdx.x >= off) ? s[threadIdx.x - off] : 0;
        __syncthreads();
        s[threadIdx.x] += t;
        __syncthreads();
    }
    if (threadIdx.x < nb) boffs[threadIdx.x] = s[threadIdx.x] - v;
}

__global__ void finalize_rowptr(int* __restrict__ rowptr, const int* __restrict__ boffs,
                                int n, int E) {
    int i = blockIdx.x * 256 + threadIdx.x;
    if (i < n) rowptr[i] += boffs[blockIdx.x];
    if (i == 0) rowptr[n] = E;
}

__global__ __launch_bounds__(256) void place_kernel(
    const int* __restrict__ src, const int* __restrict__ dst,
    const int* __restrict__ pos, const int* __restrict__ rowptr,
    int* __restrict__ csr, int E) {
    int i4 = (blockIdx.x * 256 + threadIdx.x) * 4;
    if (i4 + 3 < E) {
        int4 s = *(const int4*)(src + i4);
        int4 d = *(const int4*)(dst + i4);
        int4 p = *(const int4*)(pos + i4);
        csr[rowptr[d.x] + p.x] = s.x;
        csr[rowptr[d.y] + p.y] = s.y;
        csr[rowptr[d.z] + p.z] = s.z;
        csr[rowptr[d.w] + p.w] = s.w;
    } else {
        for (int e = i4; e < E; e++)
            csr[rowptr[dst[e]] + pos[e]] = src[e];
    }
}

// --------------- both weight transposes + bf16 convert, one launch ---------
__global__ void wcvt2_kernel(const float* __restrict__ W1, const float* __restrict__ W2,
                             ushort_t* __restrict__ W1t, ushort_t* __restrict__ W2t) {
    int i = blockIdx.x * 256 + threadIdx.x;
    if (i < 256 * 128) {
        int k = i / 128, n = i % 128;
        W1t[n * 256 + k] = f2bf(W1[i]);
    }
    int j = i - 256 * 128;
    if (j >= 0 && j < 128 * 64) {
        int k = j / 64, n = j % 64;
        W2t[n * 128 + k] = f2bf(W2[j]);
    }
}

// ------------------------------ GEMM 1 -------------------------------------
// out[m][n] = bf16(dinv[m] * sum_k x[m][k]*W1t[n][k]), M x 256 x 128.
// BM=128, BK=32, 4 waves in 2x2 grid (wave = 64m x 64n), LDS double-buffered
// via global_load_lds. A fp32 in LDS (cvt after ds_read), B bf16 in LDS.
__global__ __launch_bounds__(256) void gemm1_mfma(
    const float* __restrict__ A, const ushort_t* __restrict__ Bt,
    const float* __restrict__ dinv, ushort_t* __restrict__ out, int M) {
    __shared__ float    As[2][128 * 32];   // 16 KB per buf
    __shared__ ushort_t Bs[2][128 * 32];   // 8 KB per buf
    const int tid = threadIdx.x;
    const int l = tid & 63;
    const int wave = tid >> 6;
    const int wm = wave >> 1, wn = wave & 1;
    const int lrow = l & 15, hh = l >> 4;
    const int m0 = blockIdx.x * 128;

    // LDS slots (element offsets), swizzle matches staging below
    int aslot0[4], aslot1[4], bslot[4];
    #pragma unroll
    for (int mt = 0; mt < 4; mt++) {
        int r = wm * 64 + mt * 16 + lrow;
        int sw = r & 7;
        aslot0[mt] = (r * 8 + ((2 * hh) ^ sw)) * 4;
        aslot1[mt] = (r * 8 + ((2 * hh + 1) ^ sw)) * 4;
    }
    #pragma unroll
    for (int nt = 0; nt < 4; nt++) {
        int nc = wn * 64 + nt * 16 + lrow;
        bslot[nt] = (nc * 4 + (hh ^ ((nc >> 2) & 3))) * 8;
    }

    floatx4 acc[4][4];
    #pragma unroll
    for (int mt = 0; mt < 4; mt++)
        #pragma unroll
        for (int nt = 0; nt < 4; nt++)
            acc[mt][nt] = (floatx4){0.f, 0.f, 0.f, 0.f};

    auto stage = [&](int buf, int k0) {
        #pragma unroll
        for (int i = 0; i < 4; i++) {           // A: 1024 x 16B
            int s = i * 256 + tid;
            int r = s >> 3, cp = s & 7;
            int cg = cp ^ (r & 7);
            int row = m0 + r; if (row >= M) row = M - 1;
            ld_lds16(&As[buf][s * 4], A + (size_t)row * 256 + k0 + cg * 4);
        }
        #pragma unroll
        for (int i = 0; i < 2; i++) {           // B: 512 x 16B
            int s = i * 256 + tid;
            int nn = s >> 2, cp = s & 3;
            int cg = cp ^ ((nn >> 2) & 3);
            ld_lds16(&Bs[buf][s * 8], Bt + (size_t)nn * 256 + k0 + cg * 8);
        }
    };

    stage(0, 0);
    __syncthreads();
    int buf = 0;
    for (int kk = 0; kk < 8; kk++) {
        if (kk < 7) stage(buf ^ 1, (kk + 1) * 32);
        short8 afr[4], bfr[4];
        #pragma unroll
        for (int mt = 0; mt < 4; mt++) {
            float4 u = *(const float4*)&As[buf][aslot0[mt]];
            float4 v = *(const float4*)&As[buf][aslot1[mt]];
            short8 t;
            t[0] = (short)f2bf(u.x); t[1] = (short)f2bf(u.y);
            t[2] = (short)f2bf(u.z); t[3] = (short)f2bf(u.w);
            t[4] = (short)f2bf(v.x); t[5] = (short)f2bf(v.y);
            t[6] = (short)f2bf(v.z); t[7] = (short)f2bf(v.w);
            afr[mt] = t;
        }
        #pragma unroll
        for (int nt = 0; nt < 4; nt++)
            bfr[nt] = *(const short8*)&Bs[buf][bslot[nt]];
        #pragma unroll
        for (int mt = 0; mt < 4; mt++)
            #pragma unroll
            for (int nt = 0; nt < 4; nt++)
                acc[mt][nt] = __builtin_amdgcn_mfma_f32_16x16x32_bf16(
                    afr[mt], bfr[nt], acc[mt][nt], 0, 0, 0);
        __syncthreads();
        buf ^= 1;
    }

    const int r0 = hh * 4;
    #pragma unroll
    for (int mt = 0; mt < 4; mt++) {
        int mbase = m0 + wm * 64 + mt * 16 + r0;
        float4 dv = *(const float4*)&dinv[mbase];   // dinv padded past N
        float d[4] = {dv.x, dv.y, dv.z, dv.w};
        #pragma unroll
        for (int i = 0; i < 4; i++) {
            int m = mbase + i;
            if (m < M) {
                #pragma unroll
                for (int nt = 0; nt < 4; nt++)
                    out[(size_t)m * 128 + wn * 64 + nt * 16 + lrow] =
                        f2bf(acc[mt][nt][i] * d[i]);
            }
        }
    }
}

// ------------------------------ GEMM 2 -------------------------------------
// out[m][n] = bf16(dinv[m] * sum_k h1[m][k]*W2t[n][k]), M x 128 x 64. All bf16.
__global__ __launch_bounds__(256) void gemm2_mfma(
    const ushort_t* __restrict__ A, const ushort_t* __restrict__ Bt,
    const float* __restrict__ dinv, ushort_t* __restrict__ out, int M) {
    __shared__ ushort_t As[2][128 * 32];   // 8 KB per buf
    __shared__ ushort_t Bs[2][64 * 32];    // 4 KB per buf
    const int tid = threadIdx.x;
    const int l = tid & 63;
    const int wave = tid >> 6;
    const int wm = wave >> 1, wn = wave & 1;
    const int lrow = l & 15, hh = l >> 4;
    const int m0 = blockIdx.x * 128;

    int aslot[4], bslot[2];
    #pragma unroll
    for (int mt = 0; mt < 4; mt++) {
        int r = wm * 64 + mt * 16 + lrow;
        aslot[mt] = (r * 4 + (hh ^ ((r >> 2) & 3))) * 8;
    }
    #pragma unroll
    for (int nt = 0; nt < 2; nt++) {
        int nc = wn * 32 + nt * 16 + lrow;
        bslot[nt] = (nc * 4 + (hh ^ ((nc >> 2) & 3))) * 8;
    }

    floatx4 acc[4][2];
    #pragma unroll
    for (int mt = 0; mt < 4; mt++)
        #pragma unroll
        for (int nt = 0; nt < 2; nt++)
            acc[mt][nt] = (floatx4){0.f, 0.f, 0.f, 0.f};

    auto stage = [&](int buf, int k0) {
        #pragma unroll
        for (int i = 0; i < 2; i++) {           // A: 512 x 16B
            int s = i * 256 + tid;
            int r = s >> 2, cp = s & 3;
            int cg = cp ^ ((r >> 2) & 3);
            int row = m0 + r; if (row >= M) row = M - 1;
            ld_lds16(&As[buf][s * 8], A + (size_t)row * 128 + k0 + cg * 8);
        }
        {                                        // B: 256 x 16B
            int s = tid;
            int nn = s >> 2, cp = s & 3;
            int cg = cp ^ ((nn >> 2) & 3);
            ld_lds16(&Bs[buf][s * 8], Bt + (size_t)nn * 128 + k0 + cg * 8);
        }
    };

    stage(0, 0);
    __syncthreads();
    int buf = 0;
    for (int kk = 0; kk < 4; kk++) {
        if (kk < 3) stage(buf ^ 1, (kk + 1) * 32);
        short8 afr[4], bfr[2];
        #pragma unroll
        for (int mt = 0; mt < 4; mt++)
            afr[mt] = *(const short8*)&As[buf][aslot[mt]];
        #pragma unroll
        for (int nt = 0; nt < 2; nt++)
            bfr[nt] = *(const short8*)&Bs[buf][bslot[nt]];
        #pragma unroll
        for (int mt = 0; mt < 4; mt++)
            #pragma unroll
            for (int nt = 0; nt < 2; nt++)
                acc[mt][nt] = __builtin_amdgcn_mfma_f32_16x16x32_bf16(
                    afr[mt], bfr[nt], acc[mt][nt], 0, 0, 0);
        __syncthreads();
        buf ^= 1;
    }

    const int r0 = hh * 4;
    #pragma unroll
    for (int mt = 0; mt < 4; mt++) {
        int mbase = m0 + wm * 64 + mt * 16 + r0;
        float4 dv = *(const float4*)&dinv[mbase];
        float d[4] = {dv.x, dv.y, dv.z, dv.w};
        #pragma unroll
        for (int i = 0; i < 4; i++) {
            int m = mbase + i;
            if (m < M) {
                #pragma unroll
                for (int nt = 0; nt < 2; nt++)
                    out[(size_t)m * 64 + wn * 32 + nt * 16 + lrow] =
                        f2bf(acc[mt][nt][i] * d[i]);
            }
        }
    }
}

// ------------------------------ SpMM 1 -------------------------------------
__global__ __launch_bounds__(256) void spmm_relu128(
    const ushort_t* __restrict__ Mm, const int* __restrict__ rowptr,
    const int* __restrict__ csr, const float* __restrict__ dinv,
    const float* __restrict__ bias, ushort_t* __restrict__ out, int n) {
    int v = (blockIdx.x * 256 + threadIdx.x) >> 6;
    int lane = threadIdx.x & 63;
    if (v >= n) return;
    int jb = rowptr[v], je = rowptr[v + 1];
    int cntn = je - jb;

    float2 accA = up2(*(const uint_t*)(Mm + (size_t)v * 128 + lane * 2));  // self
    float2 accB = make_float2(0.f, 0.f);

    for (int base = 0; base < cntn; base += 64) {
        int m = cntn - base; if (m > 64) m = 64;
        int idx = (base + lane < cntn) ? csr[jb + base + lane] : 0;
        int jj = 0;
        for (; jj + 16 <= m; jj += 16) {
            int sI[16];
            #pragma unroll
            for (int t = 0; t < 16; t++) sI[t] = __shfl(idx, jj + t);
            uint_t p[16];
            #pragma unroll
            for (int t = 0; t < 16; t++)
                p[t] = *(const uint_t*)(Mm + (size_t)sI[t] * 128 + lane * 2);
            #pragma unroll
            for (int t = 0; t < 16; t++) {
                float2 f = up2(p[t]);
                if (t & 1) { accB.x += f.x; accB.y += f.y; }
                else       { accA.x += f.x; accA.y += f.y; }
            }
        }
        for (; jj + 8 <= m; jj += 8) {
            int sI[8];
            #pragma unroll
            for (int t = 0; t < 8; t++) sI[t] = __shfl(idx, jj + t);
            uint_t p[8];
            #pragma unroll
            for (int t = 0; t < 8; t++)
                p[t] = *(const uint_t*)(Mm + (size_t)sI[t] * 128 + lane * 2);
            #pragma unroll
            for (int t = 0; t < 8; t++) {
                float2 f = up2(p[t]);
                if (t & 1) { accB.x += f.x; accB.y += f.y; }
                else       { accA.x += f.x; accA.y += f.y; }
            }
        }
        for (; jj < m; jj++) {
            int s = __shfl(idx, jj);
            float2 f = up2(*(const uint_t*)(Mm + (size_t)s * 128 + lane * 2));
            accA.x += f.x; accA.y += f.y;
        }
    }
    float d = dinv[v];
    float2 bv = *(const float2*)&bias[lane * 2];
    float rx = fmaxf(d * (accA.x + accB.x) + bv.x, 0.f);
    float ry = fmaxf(d * (accA.y + accB.y) + bv.y, 0.f);
    uint_t packed = ((uint_t)f2bf(ry) << 16) | (uint_t)f2bf(rx);
    *(uint_t*)(out + (size_t)v * 128 + lane * 2) = packed;
}

// ------------------------------ SpMM 2 -------------------------------------
__global__ __launch_bounds__(256) void spmm_relu64(
    const ushort_t* __restrict__ Mm, const int* __restrict__ rowptr,
    const int* __restrict__ csr, const float* __restrict__ dinv,
    const float* __restrict__ bias, ushort_t* __restrict__ out, int n) {
    int v = (blockIdx.x * 256 + threadIdx.x) >> 6;
    int lane = threadIdx.x & 63;
    if (v >= n) return;
    int jb = rowptr[v], je = rowptr[v + 1];
    int cntn = je - jb;

    float accA = bf2f(Mm[(size_t)v * 64 + lane]);   // self
    float accB = 0.f;

    for (int base = 0; base < cntn; base += 64) {
        int m = cntn - base; if (m > 64) m = 64;
        int idx = (base + lane < cntn) ? csr[jb + base + lane] : 0;
        int jj = 0;
        for (; jj + 16 <= m; jj += 16) {
            int sI[16];
            #pragma unroll
            for (int t = 0; t < 16; t++) sI[t] = __shfl(idx, jj + t);
            ushort_t p[16];
            #pragma unroll
            for (int t = 0; t < 16; t++)
                p[t] = Mm[(size_t)sI[t] * 64 + lane];
            #pragma unroll
            for (int t = 0; t < 16; t++) {
                if (t & 1) accB += bf2f(p[t]);
                else       accA += bf2f(p[t]);
            }
        }
        for (; jj + 8 <= m; jj += 8) {
            int sI[8];
            #pragma unroll
            for (int t = 0; t < 8; t++) sI[t] = __shfl(idx, jj + t);
            ushort_t p[8];
            #pragma unroll
            for (int t = 0; t < 8; t++)
                p[t] = Mm[(size_t)sI[t] * 64 + lane];
            #pragma unroll
            for (int t = 0; t < 8; t++) {
                if (t & 1) accB += bf2f(p[t]);
                else       accA += bf2f(p[t]);
            }
        }
        for (; jj < m; jj++) {
            int s = __shfl(idx, jj);
            accA += bf2f(Mm[(size_t)s * 64 + lane]);
        }
    }
    float r = fmaxf(dinv[v] * (accA + accB) + bias[lane], 0.f);
    out[(size_t)v * 64 + lane] = f2bf(r);
}

// ------------------------------ head ---------------------------------------
__global__ __launch_bounds__(256) void head_kernel(
    const ushort_t* __restrict__ h2, const float* __restrict__ Wl,
    const float* __restrict__ bl, float* __restrict__ out, int n) {
    __shared__ float Ws[64 * 10];
    __shared__ float bs[10];
    for (int i = threadIdx.x; i < 640; i += 256) Ws[i] = Wl[i];
    if (threadIdx.x < 10) bs[threadIdx.x] = bl[threadIdx.x];
    __syncthreads();
    int v = blockIdx.x * 256 + threadIdx.x;
    if (v >= n) return;
    float acc[10];
    #pragma unroll
    for (int c = 0; c < 10; c++) acc[c] = bs[c];
    const ushort_t* hrow = &h2[(size_t)v * 64];
    #pragma unroll
    for (int k0 = 0; k0 < 64; k0 += 8) {
        short8 hv = *(const short8*)&hrow[k0];
        #pragma unroll
        for (int kk = 0; kk < 8; kk++) {
            float hf = bf2f((ushort_t)hv[kk]);
            #pragma unroll
            for (int c = 0; c < 10; c++)
                acc[c] += hf * Ws[(k0 + kk) * 10 + c];
        }
    }
    float m = acc[0];
    #pragma unroll
    for (int c = 1; c < 10; c++) m = fmaxf(m, acc[c]);
    float s = 0.f;
    #pragma unroll
    for (int c = 0; c < 10; c++) s += expf(acc[c] - m);
    float lse = logf(s);
    #pragma unroll
    for (int c = 0; c < 10; c++) out[(size_t)v * 10 + c] = acc[c] - m - lse;
}

// ------------------------------ launch -------------------------------------
extern "C" void kernel_launch(void* const* d_in, const int* in_sizes, int n_in,
                              void* d_out, int out_size, void* d_ws, size_t ws_size,
                              hipStream_t stream) {
    const float* x   = (const float*)d_in[0];
    const int*   ei  = (const int*)d_in[1];      // int32 (JAX x64 disabled)
    const float* W1  = (const float*)d_in[2];
    const float* b1  = (const float*)d_in[3];
    const float* W2  = (const float*)d_in[4];
    const float* b2  = (const float*)d_in[5];
    const float* Wl  = (const float*)d_in[6];
    const float* bl  = (const float*)d_in[7];
    float*       out = (float*)d_out;

    const int N = in_sizes[0] / 256;   // 100000
    const int E = in_sizes[1] / 2;     // 1600000
    const int* srcI = ei;
    const int* dstI = ei + E;

    char* ws = (char*)d_ws;
    size_t off = 0;
    auto alloc = [&](size_t bytes) -> void* {
        void* p = ws + off;
        off = (off + bytes + 255) & ~(size_t)255;
        return p;
    };
    int*      cnt    = (int*)alloc((size_t)N * 4);
    int*      rowptr = (int*)alloc((size_t)(N + 1) * 4);
    float*    dinv   = (float*)alloc((size_t)(N + 128) * 4);  // padded: BM=128 epilogue float4
    int*      csr    = (int*)alloc((size_t)E * 4);
    int*      pos    = (int*)alloc((size_t)E * 4);
    int*      bsums  = (int*)alloc(512 * 4);
    int*      boffs  = (int*)alloc(512 * 4);
    ushort_t* W1t    = (ushort_t*)alloc((size_t)128 * 256 * 2);
    ushort_t* W2t    = (ushort_t*)alloc((size_t)64 * 128 * 2);
    ushort_t* bufA   = (ushort_t*)alloc((size_t)N * 128 * 2); // M1' / M2' (bf16)
    ushort_t* bufB   = (ushort_t*)alloc((size_t)N * 128 * 2); // h1 / h2 (bf16)

    hipMemsetAsync(cnt, 0, (size_t)N * 4, stream);

    const int nb = (N + 255) / 256;  // 391 <= 512
    const int eb4 = (E + 1023) / 1024;
    deg_pos_kernel<<<eb4, 256, 0, stream>>>(dstI, cnt, pos, E);
    scan_block<<<nb, 256, 0, stream>>>(cnt, rowptr, bsums, dinv, N);
    scan_tops<<<1, 512, 0, stream>>>(bsums, boffs, nb);
    finalize_rowptr<<<nb, 256, 0, stream>>>(rowptr, boffs, N, E);
    place_kernel<<<eb4, 256, 0, stream>>>(srcI, dstI, pos, rowptr, csr, E);

    wcvt2_kernel<<<(256 * 128 + 128 * 64 + 255) / 256, 256, 0, stream>>>(W1, W2, W1t, W2t);

    const int gblk = (N + 127) / 128;
    // layer 1
    gemm1_mfma<<<gblk, 256, 0, stream>>>(x, W1t, dinv, bufA, N);
    spmm_relu128<<<(N + 3) / 4, 256, 0, stream>>>(bufA, rowptr, csr, dinv, b1, bufB, N);
    // layer 2
    gemm2_mfma<<<gblk, 256, 0, stream>>>(bufB, W2t, dinv, bufA, N);
    spmm_relu64<<<(N + 3) / 4, 256, 0, stream>>>(bufA, rowptr, csr, dinv, b2, bufB, N);
    // head
    head_kernel<<<(N + 255) / 256, 256, 0, stream>>>(bufB, Wl, bl, out, N);
}

// Round 9
// 428.974 us; speedup vs baseline: 1.5531x; 1.0182x over previous
//
#include <hip/hip_runtime.h>

// ---------------------------------------------------------------------------
// GCN, bf16 data-path:
//  deg+pos (8-way privatized counters, copy=blockIdx&7) -> scan(sum of 8) ->
//  base8 -> place (atomic-free) -> GEMM1 (global_load_lds dbuf MFMA) ->
//  SpMM1 -> GEMM2 -> SpMM2 -> head.
// R8 lesson: agent-scope atomic-with-return runs ~23 G/s with 64 ops/line
// contention; privatizing 8x cuts same-line serialization. SpMM gathers now
// broadcast byte offsets (csr<<8) to cut 64-bit addr math per message.
// ---------------------------------------------------------------------------

typedef unsigned short ushort_t;
typedef unsigned int uint_t;
typedef __attribute__((ext_vector_type(8))) short short8;
typedef __attribute__((ext_vector_type(4))) float floatx4;

static __device__ __forceinline__ ushort_t f2bf(float f) {
    union { float f; uint_t u; } c; c.f = f;
    return (ushort_t)((c.u + 0x8000u) >> 16);
}
static __device__ __forceinline__ float bf2f(ushort_t h) {
    union { uint_t u; float f; } c; c.u = ((uint_t)h) << 16;
    return c.f;
}
static __device__ __forceinline__ float2 up2(uint_t p) {
    union { uint_t u; float f; } lo, hi;
    lo.u = p << 16; hi.u = p & 0xffff0000u;
    return make_float2(lo.f, hi.f);
}
// async global->LDS, 16B per lane; LDS dst = wave-uniform base + lane*16.
static __device__ __forceinline__ void ld_lds16(void* lds, const void* g) {
    __builtin_amdgcn_global_load_lds(
        (const __attribute__((address_space(1))) unsigned int*)g,
        (__attribute__((address_space(3))) unsigned int*)lds, 16, 0, 0);
}

// ------------------------------ CSR build ----------------------------------

// pass 1: 8-way privatized degree count + slot. 8 edges/thread.
__global__ __launch_bounds__(256) void deg_pos_kernel(
    const int* __restrict__ dst, int* __restrict__ cnt8, int* __restrict__ pos,
    int E, int N) {
    int* cnt = cnt8 + (size_t)(blockIdx.x & 7) * N;
    int i8 = (blockIdx.x * 256 + threadIdx.x) * 8;
    if (i8 + 7 < E) {
        int4 d0 = *(const int4*)(dst + i8);
        int4 d1 = *(const int4*)(dst + i8 + 4);
        int4 p0, p1;
        p0.x = atomicAdd(&cnt[d0.x], 1);
        p0.y = atomicAdd(&cnt[d0.y], 1);
        p0.z = atomicAdd(&cnt[d0.z], 1);
        p0.w = atomicAdd(&cnt[d0.w], 1);
        p1.x = atomicAdd(&cnt[d1.x], 1);
        p1.y = atomicAdd(&cnt[d1.y], 1);
        p1.z = atomicAdd(&cnt[d1.z], 1);
        p1.w = atomicAdd(&cnt[d1.w], 1);
        *(int4*)(pos + i8) = p0;
        *(int4*)(pos + i8 + 4) = p1;
    } else {
        for (int e = i8; e < E; e++)
            pos[e] = atomicAdd(&cnt[dst[e]], 1);
    }
}

// scan over deg = sum of 8 copies; dinv fused.
__global__ void scan_block(const int* __restrict__ cnt8, int* __restrict__ rowptr,
                           int* __restrict__ bsums, float* __restrict__ dinv,
                           int n, int N) {
    __shared__ int s[256];
    int i = blockIdx.x * 256 + threadIdx.x;
    int v = 0;
    if (i < n) {
        #pragma unroll
        for (int c = 0; c < 8; c++) v += cnt8[(size_t)c * N + i];
        dinv[i] = rsqrtf((float)(v + 1));   // +1 self loop
    }
    s[threadIdx.x] = v;
    __syncthreads();
    for (int off = 1; off < 256; off <<= 1) {
        int t = (threadIdx.x >= off) ? s[threadIdx.x - off] : 0;
        __syncthreads();
        s[threadIdx.x] += t;
        __syncthreads();
    }
    if (i < n) rowptr[i] = s[threadIdx.x] - v;
    if (threadIdx.x == 255) bsums[blockIdx.x] = s[255];
}

__global__ void scan_tops(const int* __restrict__ bsums, int* __restrict__ boffs, int nb) {
    __shared__ int s[512];
    int v = (threadIdx.x < nb) ? bsums[threadIdx.x] : 0;
    s[threadIdx.x] = v;
    __syncthreads();
    for (int off = 1; off < 512; off <<= 1) {
        int t = (threadIdx.x >= off) ? s[threadIdx.x - off] : 0;
        __syncthreads();
        s[threadIdx.x] += t;
        __syncthreads();
    }
    if (threadIdx.x < nb) boffs[threadIdx.x] = s[threadIdx.x] - v;
}

__global__ void finalize_rowptr(int* __restrict__ rowptr, const int* __restrict__ boffs,
                                int n, int E) {
    int i = blockIdx.x * 256 + threadIdx.x;
    if (i < n) rowptr[i] += boffs[blockIdx.x];
    if (i == 0) rowptr[n] = E;
}

// base8[c][n] = rowptr[n] + sum_{c'<c} cnt8[c'][n]
__global__ void base_kernel(const int* __restrict__ cnt8, const int* __restrict__ rowptr,
                            int* __restrict__ base8, int n, int N) {
    int i = blockIdx.x * 256 + threadIdx.x;
    if (i < n) {
        int b = rowptr[i];
        #pragma unroll
        for (int c = 0; c < 8; c++) {
            base8[(size_t)c * N + i] = b;
            b += cnt8[(size_t)c * N + i];
        }
    }
}

// pass 2: placement, no atomics. Grid/indexing identical to deg_pos so
// copy = blockIdx&7 matches.
__global__ __launch_bounds__(256) void place_kernel(
    const int* __restrict__ src, const int* __restrict__ dst,
    const int* __restrict__ pos, const int* __restrict__ base8,
    int* __restrict__ csr, int E, int N) {
    const int* base = base8 + (size_t)(blockIdx.x & 7) * N;
    int i8 = (blockIdx.x * 256 + threadIdx.x) * 8;
    if (i8 + 7 < E) {
        int4 s0 = *(const int4*)(src + i8);
        int4 s1 = *(const int4*)(src + i8 + 4);
        int4 d0 = *(const int4*)(dst + i8);
        int4 d1 = *(const int4*)(dst + i8 + 4);
        int4 p0 = *(const int4*)(pos + i8);
        int4 p1 = *(const int4*)(pos + i8 + 4);
        csr[base[d0.x] + p0.x] = s0.x;
        csr[base[d0.y] + p0.y] = s0.y;
        csr[base[d0.z] + p0.z] = s0.z;
        csr[base[d0.w] + p0.w] = s0.w;
        csr[base[d1.x] + p1.x] = s1.x;
        csr[base[d1.y] + p1.y] = s1.y;
        csr[base[d1.z] + p1.z] = s1.z;
        csr[base[d1.w] + p1.w] = s1.w;
    } else {
        for (int e = i8; e < E; e++)
            csr[base[dst[e]] + pos[e]] = src[e];
    }
}

// --------------- both weight transposes + bf16 convert, one launch ---------
__global__ void wcvt2_kernel(const float* __restrict__ W1, const float* __restrict__ W2,
                             ushort_t* __restrict__ W1t, ushort_t* __restrict__ W2t) {
    int i = blockIdx.x * 256 + threadIdx.x;
    if (i < 256 * 128) {
        int k = i / 128, n = i % 128;
        W1t[n * 256 + k] = f2bf(W1[i]);
    }
    int j = i - 256 * 128;
    if (j >= 0 && j < 128 * 64) {
        int k = j / 64, n = j % 64;
        W2t[n * 128 + k] = f2bf(W2[j]);
    }
}

// ------------------------------ GEMM 1 -------------------------------------
__global__ __launch_bounds__(256) void gemm1_mfma(
    const float* __restrict__ A, const ushort_t* __restrict__ Bt,
    const float* __restrict__ dinv, ushort_t* __restrict__ out, int M) {
    __shared__ float    As[2][128 * 32];   // 16 KB per buf
    __shared__ ushort_t Bs[2][128 * 32];   // 8 KB per buf
    const int tid = threadIdx.x;
    const int l = tid & 63;
    const int wave = tid >> 6;
    const int wm = wave >> 1, wn = wave & 1;
    const int lrow = l & 15, hh = l >> 4;
    const int m0 = blockIdx.x * 128;

    int aslot0[4], aslot1[4], bslot[4];
    #pragma unroll
    for (int mt = 0; mt < 4; mt++) {
        int r = wm * 64 + mt * 16 + lrow;
        int sw = r & 7;
        aslot0[mt] = (r * 8 + ((2 * hh) ^ sw)) * 4;
        aslot1[mt] = (r * 8 + ((2 * hh + 1) ^ sw)) * 4;
    }
    #pragma unroll
    for (int nt = 0; nt < 4; nt++) {
        int nc = wn * 64 + nt * 16 + lrow;
        bslot[nt] = (nc * 4 + (hh ^ ((nc >> 2) & 3))) * 8;
    }

    floatx4 acc[4][4];
    #pragma unroll
    for (int mt = 0; mt < 4; mt++)
        #pragma unroll
        for (int nt = 0; nt < 4; nt++)
            acc[mt][nt] = (floatx4){0.f, 0.f, 0.f, 0.f};

    auto stage = [&](int buf, int k0) {
        #pragma unroll
        for (int i = 0; i < 4; i++) {           // A: 1024 x 16B
            int s = i * 256 + tid;
            int r = s >> 3, cp = s & 7;
            int cg = cp ^ (r & 7);
            int row = m0 + r; if (row >= M) row = M - 1;
            ld_lds16(&As[buf][s * 4], A + (size_t)row * 256 + k0 + cg * 4);
        }
        #pragma unroll
        for (int i = 0; i < 2; i++) {           // B: 512 x 16B
            int s = i * 256 + tid;
            int nn = s >> 2, cp = s & 3;
            int cg = cp ^ ((nn >> 2) & 3);
            ld_lds16(&Bs[buf][s * 8], Bt + (size_t)nn * 256 + k0 + cg * 8);
        }
    };

    stage(0, 0);
    __syncthreads();
    int buf = 0;
    for (int kk = 0; kk < 8; kk++) {
        if (kk < 7) stage(buf ^ 1, (kk + 1) * 32);
        short8 afr[4], bfr[4];
        #pragma unroll
        for (int mt = 0; mt < 4; mt++) {
            float4 u = *(const float4*)&As[buf][aslot0[mt]];
            float4 v = *(const float4*)&As[buf][aslot1[mt]];
            short8 t;
            t[0] = (short)f2bf(u.x); t[1] = (short)f2bf(u.y);
            t[2] = (short)f2bf(u.z); t[3] = (short)f2bf(u.w);
            t[4] = (short)f2bf(v.x); t[5] = (short)f2bf(v.y);
            t[6] = (short)f2bf(v.z); t[7] = (short)f2bf(v.w);
            afr[mt] = t;
        }
        #pragma unroll
        for (int nt = 0; nt < 4; nt++)
            bfr[nt] = *(const short8*)&Bs[buf][bslot[nt]];
        #pragma unroll
        for (int mt = 0; mt < 4; mt++)
            #pragma unroll
            for (int nt = 0; nt < 4; nt++)
                acc[mt][nt] = __builtin_amdgcn_mfma_f32_16x16x32_bf16(
                    afr[mt], bfr[nt], acc[mt][nt], 0, 0, 0);
        __syncthreads();
        buf ^= 1;
    }

    const int r0 = hh * 4;
    #pragma unroll
    for (int mt = 0; mt < 4; mt++) {
        int mbase = m0 + wm * 64 + mt * 16 + r0;
        float4 dv = *(const float4*)&dinv[mbase];   // dinv padded past N
        float d[4] = {dv.x, dv.y, dv.z, dv.w};
        #pragma unroll
        for (int i = 0; i < 4; i++) {
            int m = mbase + i;
            if (m < M) {
                #pragma unroll
                for (int nt = 0; nt < 4; nt++)
                    out[(size_t)m * 128 + wn * 64 + nt * 16 + lrow] =
                        f2bf(acc[mt][nt][i] * d[i]);
            }
        }
    }
}

// ------------------------------ GEMM 2 -------------------------------------
__global__ __launch_bounds__(256) void gemm2_mfma(
    const ushort_t* __restrict__ A, const ushort_t* __restrict__ Bt,
    const float* __restrict__ dinv, ushort_t* __restrict__ out, int M) {
    __shared__ ushort_t As[2][128 * 32];   // 8 KB per buf
    __shared__ ushort_t Bs[2][64 * 32];    // 4 KB per buf
    const int tid = threadIdx.x;
    const int l = tid & 63;
    const int wave = tid >> 6;
    const int wm = wave >> 1, wn = wave & 1;
    const int lrow = l & 15, hh = l >> 4;
    const int m0 = blockIdx.x * 128;

    int aslot[4], bslot[2];
    #pragma unroll
    for (int mt = 0; mt < 4; mt++) {
        int r = wm * 64 + mt * 16 + lrow;
        aslot[mt] = (r * 4 + (hh ^ ((r >> 2) & 3))) * 8;
    }
    #pragma unroll
    for (int nt = 0; nt < 2; nt++) {
        int nc = wn * 32 + nt * 16 + lrow;
        bslot[nt] = (nc * 4 + (hh ^ ((nc >> 2) & 3))) * 8;
    }

    floatx4 acc[4][2];
    #pragma unroll
    for (int mt = 0; mt < 4; mt++)
        #pragma unroll
        for (int nt = 0; nt < 2; nt++)
            acc[mt][nt] = (floatx4){0.f, 0.f, 0.f, 0.f};

    auto stage = [&](int buf, int k0) {
        #pragma unroll
        for (int i = 0; i < 2; i++) {           // A: 512 x 16B
            int s = i * 256 + tid;
            int r = s >> 2, cp = s & 3;
            int cg = cp ^ ((r >> 2) & 3);
            int row = m0 + r; if (row >= M) row = M - 1;
            ld_lds16(&As[buf][s * 8], A + (size_t)row * 128 + k0 + cg * 8);
        }
        {                                        // B: 256 x 16B
            int s = tid;
            int nn = s >> 2, cp = s & 3;
            int cg = cp ^ ((nn >> 2) & 3);
            ld_lds16(&Bs[buf][s * 8], Bt + (size_t)nn * 128 + k0 + cg * 8);
        }
    };

    stage(0, 0);
    __syncthreads();
    int buf = 0;
    for (int kk = 0; kk < 4; kk++) {
        if (kk < 3) stage(buf ^ 1, (kk + 1) * 32);
        short8 afr[4], bfr[2];
        #pragma unroll
        for (int mt = 0; mt < 4; mt++)
            afr[mt] = *(const short8*)&As[buf][aslot[mt]];
        #pragma unroll
        for (int nt = 0; nt < 2; nt++)
            bfr[nt] = *(const short8*)&Bs[buf][bslot[nt]];
        #pragma unroll
        for (int mt = 0; mt < 4; mt++)
            #pragma unroll
            for (int nt = 0; nt < 2; nt++)
                acc[mt][nt] = __builtin_amdgcn_mfma_f32_16x16x32_bf16(
                    afr[mt], bfr[nt], acc[mt][nt], 0, 0, 0);
        __syncthreads();
        buf ^= 1;
    }

    const int r0 = hh * 4;
    #pragma unroll
    for (int mt = 0; mt < 4; mt++) {
        int mbase = m0 + wm * 64 + mt * 16 + r0;
        float4 dv = *(const float4*)&dinv[mbase];
        float d[4] = {dv.x, dv.y, dv.z, dv.w};
        #pragma unroll
        for (int i = 0; i < 4; i++) {
            int m = mbase + i;
            if (m < M) {
                #pragma unroll
                for (int nt = 0; nt < 2; nt++)
                    out[(size_t)m * 64 + wn * 32 + nt * 16 + lrow] =
                        f2bf(acc[mt][nt][i] * d[i]);
            }
        }
    }
}

// ------------------------------ SpMM 1 -------------------------------------
// F=128, bf16 in/out. Byte-row-offset broadcast (csr<<8) to cut addr math.
__global__ __launch_bounds__(256) void spmm_relu128(
    const ushort_t* __restrict__ Mm, const int* __restrict__ rowptr,
    const int* __restrict__ csr, const float* __restrict__ dinv,
    const float* __restrict__ bias, ushort_t* __restrict__ out, int n) {
    int v = (blockIdx.x * 256 + threadIdx.x) >> 6;
    int lane = threadIdx.x & 63;
    if (v >= n) return;
    int jb = rowptr[v], je = rowptr[v + 1];
    int cntn = je - jb;
    const char* Mb = (const char*)Mm;
    const uint_t loff = lane * 4;

    float2 accA = up2(*(const uint_t*)(Mb + ((size_t)v << 8) + loff));  // self
    float2 accB = make_float2(0.f, 0.f);

    for (int base = 0; base < cntn; base += 64) {
        int m = cntn - base; if (m > 64) m = 64;
        int roff = (base + lane < cntn) ? (csr[jb + base + lane] << 8) : 0;
        int jj = 0;
        for (; jj + 16 <= m; jj += 16) {
            uint_t o[16];
            #pragma unroll
            for (int t = 0; t < 16; t++) o[t] = (uint_t)__shfl(roff, jj + t) + loff;
            uint_t p[16];
            #pragma unroll
            for (int t = 0; t < 16; t++) p[t] = *(const uint_t*)(Mb + o[t]);
            #pragma unroll
            for (int t = 0; t < 16; t++) {
                float2 f = up2(p[t]);
                if (t & 1) { accB.x += f.x; accB.y += f.y; }
                else       { accA.x += f.x; accA.y += f.y; }
            }
        }
        for (; jj + 8 <= m; jj += 8) {
            uint_t o[8];
            #pragma unroll
            for (int t = 0; t < 8; t++) o[t] = (uint_t)__shfl(roff, jj + t) + loff;
            uint_t p[8];
            #pragma unroll
            for (int t = 0; t < 8; t++) p[t] = *(const uint_t*)(Mb + o[t]);
            #pragma unroll
            for (int t = 0; t < 8; t++) {
                float2 f = up2(p[t]);
                if (t & 1) { accB.x += f.x; accB.y += f.y; }
                else       { accA.x += f.x; accA.y += f.y; }
            }
        }
        for (; jj < m; jj++) {
            uint_t o = (uint_t)__shfl(roff, jj) + loff;
            float2 f = up2(*(const uint_t*)(Mb + o));
            accA.x += f.x; accA.y += f.y;
        }
    }
    float d = dinv[v];
    float2 bv = *(const float2*)&bias[lane * 2];
    float rx = fmaxf(d * (accA.x + accB.x) + bv.x, 0.f);
    float ry = fmaxf(d * (accA.y + accB.y) + bv.y, 0.f);
    uint_t packed = ((uint_t)f2bf(ry) << 16) | (uint_t)f2bf(rx);
    *(uint_t*)(out + (size_t)v * 128 + lane * 2) = packed;
}

// ------------------------------ SpMM 2 -------------------------------------
// F=64, bf16 in/out. Byte-row-offset broadcast (csr<<7).
__global__ __launch_bounds__(256) void spmm_relu64(
    const ushort_t* __restrict__ Mm, const int* __restrict__ rowptr,
    const int* __restrict__ csr, const float* __restrict__ dinv,
    const float* __restrict__ bias, ushort_t* __restrict__ out, int n) {
    int v = (blockIdx.x * 256 + threadIdx.x) >> 6;
    int lane = threadIdx.x & 63;
    if (v >= n) return;
    int jb = rowptr[v], je = rowptr[v + 1];
    int cntn = je - jb;
    const char* Mb = (const char*)Mm;
    const uint_t loff = lane * 2;

    float accA = bf2f(*(const ushort_t*)(Mb + ((size_t)v << 7) + loff));  // self
    float accB = 0.f;

    for (int base = 0; base < cntn; base += 64) {
        int m = cntn - base; if (m > 64) m = 64;
        int roff = (base + lane < cntn) ? (csr[jb + base + lane] << 7) : 0;
        int jj = 0;
        for (; jj + 16 <= m; jj += 16) {
            uint_t o[16];
            #pragma unroll
            for (int t = 0; t < 16; t++) o[t] = (uint_t)__shfl(roff, jj + t) + loff;
            ushort_t p[16];
            #pragma unroll
            for (int t = 0; t < 16; t++) p[t] = *(const ushort_t*)(Mb + o[t]);
            #pragma unroll
            for (int t = 0; t < 16; t++) {
                if (t & 1) accB += bf2f(p[t]);
                else       accA += bf2f(p[t]);
            }
        }
        for (; jj + 8 <= m; jj += 8) {
            uint_t o[8];
            #pragma unroll
            for (int t = 0; t < 8; t++) o[t] = (uint_t)__shfl(roff, jj + t) + loff;
            ushort_t p[8];
            #pragma unroll
            for (int t = 0; t < 8; t++) p[t] = *(const ushort_t*)(Mb + o[t]);
            #pragma unroll
            for (int t = 0; t < 8; t++) {
                if (t & 1) accB += bf2f(p[t]);
                else       accA += bf2f(p[t]);
            }
        }
        for (; jj < m; jj++) {
            uint_t o = (uint_t)__shfl(roff, jj) + loff;
            accA += bf2f(*(const ushort_t*)(Mb + o));
        }
    }
    float r = fmaxf(dinv[v] * (accA + accB) + bias[lane], 0.f);
    out[(size_t)v * 64 + lane] = f2bf(r);
}

// ------------------------------ head ---------------------------------------
__global__ __launch_bounds__(256) void head_kernel(
    const ushort_t* __restrict__ h2, const float* __restrict__ Wl,
    const float* __restrict__ bl, float* __restrict__ out, int n) {
    __shared__ float Ws[64 * 10];
    __shared__ float bs[10];
    for (int i = threadIdx.x; i < 640; i += 256) Ws[i] = Wl[i];
    if (threadIdx.x < 10) bs[threadIdx.x] = bl[threadIdx.x];
    __syncthreads();
    int v = blockIdx.x * 256 + threadIdx.x;
    if (v >= n) return;
    float acc[10];
    #pragma unroll
    for (int c = 0; c < 10; c++) acc[c] = bs[c];
    const ushort_t* hrow = &h2[(size_t)v * 64];
    #pragma unroll
    for (int k0 = 0; k0 < 64; k0 += 8) {
        short8 hv = *(const short8*)&hrow[k0];
        #pragma unroll
        for (int kk = 0; kk < 8; kk++) {
            float hf = bf2f((ushort_t)hv[kk]);
            #pragma unroll
            for (int c = 0; c < 10; c++)
                acc[c] += hf * Ws[(k0 + kk) * 10 + c];
        }
    }
    float m = acc[0];
    #pragma unroll
    for (int c = 1; c < 10; c++) m = fmaxf(m, acc[c]);
    float s = 0.f;
    #pragma unroll
    for (int c = 0; c < 10; c++) s += expf(acc[c] - m);
    float lse = logf(s);
    #pragma unroll
    for (int c = 0; c < 10; c++) out[(size_t)v * 10 + c] = acc[c] - m - lse;
}

// ------------------------------ launch -------------------------------------
extern "C" void kernel_launch(void* const* d_in, const int* in_sizes, int n_in,
                              void* d_out, int out_size, void* d_ws, size_t ws_size,
                              hipStream_t stream) {
    const float* x   = (const float*)d_in[0];
    const int*   ei  = (const int*)d_in[1];      // int32 (JAX x64 disabled)
    const float* W1  = (const float*)d_in[2];
    const float* b1  = (const float*)d_in[3];
    const float* W2  = (const float*)d_in[4];
    const float* b2  = (const float*)d_in[5];
    const float* Wl  = (const float*)d_in[6];
    const float* bl  = (const float*)d_in[7];
    float*       out = (float*)d_out;

    const int N = in_sizes[0] / 256;   // 100000
    const int E = in_sizes[1] / 2;     // 1600000
    const int* srcI = ei;
    const int* dstI = ei + E;

    char* ws = (char*)d_ws;
    size_t off = 0;
    auto alloc = [&](size_t bytes) -> void* {
        void* p = ws + off;
        off = (off + bytes + 255) & ~(size_t)255;
        return p;
    };
    int*      cnt8   = (int*)alloc((size_t)N * 8 * 4);
    int*      base8  = (int*)alloc((size_t)N * 8 * 4);
    int*      rowptr = (int*)alloc((size_t)(N + 1) * 4);
    float*    dinv   = (float*)alloc((size_t)(N + 128) * 4);  // padded: BM=128 epilogue float4
    int*      csr    = (int*)alloc((size_t)E * 4);
    int*      pos    = (int*)alloc((size_t)E * 4);
    int*      bsums  = (int*)alloc(512 * 4);
    int*      boffs  = (int*)alloc(512 * 4);
    ushort_t* W1t    = (ushort_t*)alloc((size_t)128 * 256 * 2);
    ushort_t* W2t    = (ushort_t*)alloc((size_t)64 * 128 * 2);
    ushort_t* bufA   = (ushort_t*)alloc((size_t)N * 128 * 2); // M1' / M2' (bf16)
    ushort_t* bufB   = (ushort_t*)alloc((size_t)N * 128 * 2); // h1 / h2 (bf16)

    hipMemsetAsync(cnt8, 0, (size_t)N * 8 * 4, stream);

    const int nb = (N + 255) / 256;     // 391 <= 512
    const int eb8 = (E + 2047) / 2048;  // 8 edges/thread
    deg_pos_kernel<<<eb8, 256, 0, stream>>>(dstI, cnt8, pos, E, N);
    scan_block<<<nb, 256, 0, stream>>>(cnt8, rowptr, bsums, dinv, N, N);
    scan_tops<<<1, 512, 0, stream>>>(bsums, boffs, nb);
    finalize_rowptr<<<nb, 256, 0, stream>>>(rowptr, boffs, N, E);
    base_kernel<<<nb, 256, 0, stream>>>(cnt8, rowptr, base8, N, N);
    place_kernel<<<eb8, 256, 0, stream>>>(srcI, dstI, pos, base8, csr, E, N);

    wcvt2_kernel<<<(256 * 128 + 128 * 64 + 255) / 256, 256, 0, stream>>>(W1, W2, W1t, W2t);

    const int gblk = (N + 127) / 128;
    // layer 1
    gemm1_mfma<<<gblk, 256, 0, stream>>>(x, W1t, dinv, bufA, N);
    spmm_relu128<<<(N + 3) / 4, 256, 0, stream>>>(bufA, rowptr, csr, dinv, b1, bufB, N);
    // layer 2
    gemm2_mfma<<<gblk, 256, 0, stream>>>(bufB, W2t, dinv, bufA, N);
    spmm_relu64<<<(N + 3) / 4, 256, 0, stream>>>(bufA, rowptr, csr, dinv, b2, bufB, N);
    // head
    head_kernel<<<(N + 255) / 256, 256, 0, stream>>>(bufB, Wl, bl, out, N);
}